// Round 17
// baseline (259.174 us; speedup 1.0000x reference)
//
#include <hip/hip_runtime.h>
#include <math.h>

#define B_ 2
#define L_ 2048
#define E_ 2048
#define HQ 16
#define HKV 2
#define DH 128

typedef unsigned short u16;
typedef unsigned int u32;
typedef __attribute__((ext_vector_type(8))) short short8;
typedef __attribute__((ext_vector_type(4))) float f32x4;
typedef __attribute__((ext_vector_type(16))) float f32x16;
typedef __attribute__((ext_vector_type(4))) u32 u32x4;

static __device__ __forceinline__ u16 f2bf(float f) {
  unsigned int u = __float_as_uint(f);
  unsigned int r = (u + 0x7fffu + ((u >> 16) & 1u)) >> 16;
  return (u16)r;
}
static __device__ __forceinline__ float bf2f(u16 v) {
  return __uint_as_float(((u32)v) << 16);
}

static __device__ __forceinline__ u32 cvt_pk_bf16(float lo, float hi) {
  u32 r;
  asm volatile("v_cvt_pk_bf16_f32 %0, %1, %2" : "=v"(r) : "v"(lo), "v"(hi));
  return r;
}
// swaps a's upper-half lanes with b's lower-half lanes (gfx950).
static __device__ __forceinline__ void permswap(u32& a, u32& b) {
  asm volatile("v_permlane32_swap_b32 %0, %1" : "+v"(a), "+v"(b));
}

#define GLB(p) ((const __attribute__((address_space(1))) void*)(p))
#define LDS(p) ((__attribute__((address_space(3))) void*)(p))

// ---------------------------------------------------------------------------
// fp32 -> bf16 convert
// ---------------------------------------------------------------------------
__global__ void cvt_bf16_kernel(const float* __restrict__ in,
                                u16* __restrict__ out, int n) {
  int i = (blockIdx.x * 256 + threadIdx.x) * 8;
  if (i >= n) return;
  float4 a = *reinterpret_cast<const float4*>(in + i);
  float4 b = *reinterpret_cast<const float4*>(in + i + 4);
  short8 r;
  r[0] = (short)f2bf(a.x); r[1] = (short)f2bf(a.y);
  r[2] = (short)f2bf(a.z); r[3] = (short)f2bf(a.w);
  r[4] = (short)f2bf(b.x); r[5] = (short)f2bf(b.y);
  r[6] = (short)f2bf(b.z); r[7] = (short)f2bf(b.w);
  *reinterpret_cast<short8*>(out + i) = r;
}

// ---------------------------------------------------------------------------
// RoPE table
// ---------------------------------------------------------------------------
__global__ void rope_tab_kernel(float* __restrict__ ctab, float* __restrict__ stab) {
  int idx = blockIdx.x * 256 + threadIdx.x;
  if (idx >= L_ * (DH / 2)) return;
  int pos = idx >> 6;
  int f = idx & 63;
  float inv_freq = powf(10000.0f, -(float)f * (1.0f / 64.0f));
  float ang = (float)pos * inv_freq;
  float s, c;
  sincosf(ang, &s, &c);
  ctab[idx] = c;
  stab[idx] = s;
}

// ---------------------------------------------------------------------------
// RoPE apply from bf16 fused-qkv buffer -> bf16 head-major buffer
// ---------------------------------------------------------------------------
__global__ void rope_convert_kernel(const u16* __restrict__ in,
                                    u16* __restrict__ outb,
                                    const float* __restrict__ ctab,
                                    const float* __restrict__ stab,
                                    int H, int rowStride, int colOff,
                                    float scale, int total) {
  int idx = blockIdx.x * 256 + threadIdx.x;
  if (idx >= total) return;
  int f = idx & 63;
  int row = idx >> 6;
  int h = row % H;
  int bl = row / H;
  int l = bl & (L_ - 1);
  size_t sbase = (size_t)bl * rowStride + colOff + (size_t)h * DH;
  size_t dbase = (size_t)bl * ((size_t)H * DH) + (size_t)h * DH;
  float x1 = bf2f(in[sbase + f]);
  float x2 = bf2f(in[sbase + 64 + f]);
  float c = ctab[l * 64 + f];
  float s = stab[l * 64 + f];
  outb[dbase + f]      = f2bf((x1 * c - x2 * s) * scale);
  outb[dbase + 64 + f] = f2bf((x2 * c + x1 * s) * scale);
}

// ---------------------------------------------------------------------------
// V transpose from bf16 qkv buffer: -> Vt[(b*HKV+kvh)*128+d][key]
// ---------------------------------------------------------------------------
__global__ __launch_bounds__(256) void transpose_v_kernel(
    const u16* __restrict__ v, u16* __restrict__ Vt,
    int rowStride, int colOff) {
  __shared__ u16 tile[64][68];
  const int k0 = blockIdx.x * 64;
  const int d0 = blockIdx.y * 64;
  const int bk = blockIdx.z;
  const int b = bk / HKV, kvh = bk % HKV;
#pragma unroll
  for (int i = 0; i < 4; ++i) {
    int key = i * 16 + (threadIdx.x >> 4);
    int d4 = (threadIdx.x & 15) * 4;
    *reinterpret_cast<ushort2*>(&tile[key][d4]) = *reinterpret_cast<const ushort2*>(
        &v[(size_t)(b * L_ + k0 + key) * rowStride + colOff + kvh * DH + d0 + d4]);
    *reinterpret_cast<ushort2*>(&tile[key][d4 + 2]) = *reinterpret_cast<const ushort2*>(
        &v[(size_t)(b * L_ + k0 + key) * rowStride + colOff + kvh * DH + d0 + d4 + 2]);
  }
  __syncthreads();
  const int d = threadIdx.x >> 2;
  const int kq = (threadIdx.x & 3) * 16;
  u16* orow = Vt + ((size_t)(bk * DH + d0 + d)) * L_ + k0 + kq;
#pragma unroll
  for (int j = 0; j < 16; ++j) orow[j] = tile[kq + j][d];
}

// ---------------------------------------------------------------------------
// bf16 MFMA GEMM: 128x128 tile, BK=64, single-buffer, 2x __syncthreads,
// XOR-slot LDS mapping (R14/R15-proven). 32 MFMAs per K-step.
// ---------------------------------------------------------------------------
#define GBM 128
#define GBN 128
#define GBK 64

template <bool BF16OUT>
__global__ __launch_bounds__(256) void gemm_bf16_kernel(
    const u16* __restrict__ A, const u16* __restrict__ W,
    const float* __restrict__ bias, void* __restrict__ Cv,
    int M, int N, int K)
{
  __shared__ u16 As[GBM * GBK];   // 16 KB
  __shared__ u16 Bs[GBN * GBK];   // 16 KB

  const int tid = threadIdx.x;
  const int wave = tid >> 6;
  const int lane = tid & 63;
  const int lr = lane & 15;
  const int lg = lane >> 4;
  const int bm = blockIdx.y * GBM;
  const int bn = blockIdx.x * GBN;
  const int wm = (wave >> 1) * 64;
  const int wn = (wave & 1) * 64;

  f32x4 acc[4][4];
#pragma unroll
  for (int i = 0; i < 4; ++i)
#pragma unroll
    for (int j = 0; j < 4; ++j) acc[i][j] = (f32x4){0.f, 0.f, 0.f, 0.f};

  const u16* gA[4];
  const u16* gB[4];
  u16* lA[4];
  u16* lB[4];
#pragma unroll
  for (int t = 0; t < 4; ++t) {
    int c = t * 256 + wave * 64 + lane;
    int row = c >> 3;
    int slog = (c & 7) ^ (row & 7);
    gA[t] = A + (size_t)(bm + row) * K + slog * 8;
    gB[t] = W + (size_t)(bn + row) * K + slog * 8;
    lA[t] = &As[(t * 256 + wave * 64) * 8];
    lB[t] = &Bs[(t * 256 + wave * 64) * 8];
  }

  const int fx = lr & 7;

  for (int k0 = 0; k0 < K; k0 += GBK) {
    __syncthreads();
#pragma unroll
    for (int t = 0; t < 4; ++t) {
      __builtin_amdgcn_global_load_lds(GLB(gA[t] + k0), LDS(lA[t]), 16, 0, 0);
      __builtin_amdgcn_global_load_lds(GLB(gB[t] + k0), LDS(lB[t]), 16, 0, 0);
    }
    __syncthreads();

#pragma unroll
    for (int kk = 0; kk < 2; ++kk) {
      short8 af[4], bf[4];
#pragma unroll
      for (int mi = 0; mi < 4; ++mi) {
        int row = wm + mi * 16 + lr;
        int slot = (kk * 4 + lg) ^ fx;
        af[mi] = *reinterpret_cast<const short8*>(&As[row * 64 + slot * 8]);
      }
#pragma unroll
      for (int ni = 0; ni < 4; ++ni) {
        int row = wn + ni * 16 + lr;
        int slot = (kk * 4 + lg) ^ fx;
        bf[ni] = *reinterpret_cast<const short8*>(&Bs[row * 64 + slot * 8]);
      }
#pragma unroll
      for (int mi = 0; mi < 4; ++mi)
#pragma unroll
        for (int ni = 0; ni < 4; ++ni)
          acc[mi][ni] = __builtin_amdgcn_mfma_f32_16x16x32_bf16(af[mi], bf[ni], acc[mi][ni], 0, 0, 0);
    }
  }

#pragma unroll
  for (int ni = 0; ni < 4; ++ni) {
    int col = bn + wn + ni * 16 + lr;
    float bv = (bias != nullptr) ? bias[col] : 0.f;
#pragma unroll
    for (int mi = 0; mi < 4; ++mi) {
#pragma unroll
      for (int r = 0; r < 4; ++r) {
        int row = bm + wm + mi * 16 + lg * 4 + r;
        float val = acc[mi][ni][r] + bv;
        if constexpr (BF16OUT)
          ((u16*)Cv)[(size_t)row * N + col] = f2bf(val);
        else
          ((float*)Cv)[(size_t)row * N + col] = val;
      }
    }
  }
}

// ---------------------------------------------------------------------------
// Flash attention, KVBLK=64, 2-wave blocks (2 heads), K in LDS (dbuf,
// counted-vmcnt), V direct global->reg (T14 early issue; L2-resident).
// Grid 1024 = 64 tiles x 16 (b,kvh,head-pair) combos; 4 blocks/CU resident
// (LDS 32.3 KB), constant per-CU tile sum via tile = u<32 ? 63-u : u-32.
// ---------------------------------------------------------------------------
__device__ __forceinline__ void pack16(const float p[16], short8& pa0, short8& pa1) {
  u32 w[8];
#pragma unroll
  for (int t = 0; t < 8; ++t) w[t] = cvt_pk_bf16(p[2 * t], p[2 * t + 1]);
  permswap(w[0], w[2]); permswap(w[1], w[3]);
  permswap(w[4], w[6]); permswap(w[5], w[7]);
  pa0 = __builtin_bit_cast(short8, (u32x4){w[0], w[1], w[2], w[3]});
  pa1 = __builtin_bit_cast(short8, (u32x4){w[4], w[5], w[6], w[7]});
}

__device__ __forceinline__ void head_epilogue(
    const f32x16 O[4], float lrun, int l5, int hi, float* cbufw,
    u16* __restrict__ obase)
{
  float ltot = lrun + __shfl_xor(lrun, 32);
  if (hi == 0) cbufw[l5] = ltot;
  float4 lv[4];
#pragma unroll
  for (int gg = 0; gg < 4; ++gg)
    lv[gg] = *reinterpret_cast<const float4*>(&cbufw[8 * gg + 4 * hi]);
#pragma unroll
  for (int r = 0; r < 16; ++r) {
    int crow = (r & 3) + 8 * (r >> 2) + 4 * hi;
    float inv = __builtin_amdgcn_rcpf((&lv[r >> 2].x)[r & 3]);
    u16* orow = obase + (size_t)crow * (HQ * DH) + l5;
#pragma unroll
    for (int n = 0; n < 4; ++n)
      orow[n * 32] = f2bf(O[n][r] * inv);
  }
}

__global__ __launch_bounds__(128, 2) void flash_attn_pipe_kernel(
    const u16* __restrict__ Qb, const u16* __restrict__ Kb,
    const u16* __restrict__ Vt, u16* __restrict__ ab)
{
  const int tid = threadIdx.x;
  const int wave = tid >> 6;          // 0..1
  const int lane = tid & 63;
  const int l5 = lane & 31;
  const int hi = lane >> 5;

  const int bid = blockIdx.x;
  const int u = bid >> 4;             // 0..63
  const int combo = bid & 15;
  const int hp = combo & 3;           // head-pair
  const int c = combo >> 2;
  const int b = c >> 1, kvh = c & 1;
  const int t = (u < 32) ? (63 - u) : (u - 32);
  const int h = kvh * 8 + hp * 2 + wave;
  const int q0 = 32 * t;
  const int nst = (t + 2) >> 1;       // 64-key steps
  const int bk = b * HKV + kvh;

  __shared__ u16 Ks[2][64 * 128];     // 16 KB each; phys = slot ^ (key&15)
  __shared__ __align__(16) float cbuf[2][32];
  float* cbufw = cbuf[wave];

  const u16* Kg = Kb + (size_t)(b * L_) * (HKV * DH) + kvh * DH;

  // K staging: 1024 chunks of 16B; 128 threads x 8 chunks each
  auto stage = [&](int s) {
    const int buf = s & 1;
    const int j0 = s * 64;
#pragma unroll
    for (int q = 0; q < 8; ++q) {
      int cnk = q * 128 + tid;
      int key = cnk >> 4, phys = cnk & 15;
      int slog = phys ^ (key & 15);
      const u16* src = Kg + (size_t)(j0 + key) * (HKV * DH) + slog * 8;
      __builtin_amdgcn_global_load_lds(GLB(src), LDS(&Ks[buf][(q * 128 + wave * 64) * 8]), 16, 0, 0);
    }
  };

  const u16* qrow = Qb + ((size_t)(b * L_ + q0 + l5)) * (HQ * DH) + h * DH + hi * 8;
  short8 qB[8];
#pragma unroll
  for (int ss = 0; ss < 8; ++ss)
    qB[ss] = *reinterpret_cast<const short8*>(qrow + ss * 16);

  // V direct from global (L2-resident): row d = n*32+l5, elem j0 + cc*16 + hi*8
  const u16* vbase = Vt + ((size_t)(bk * DH + l5)) * L_ + hi * 8;

  f32x16 O[4];
#pragma unroll
  for (int n = 0; n < 4; ++n)
#pragma unroll
    for (int r = 0; r < 16; ++r) O[n][r] = 0.f;
  float mrun = -INFINITY, lrun = 0.f;

  stage(0);
  if (nst > 1) stage(1);

#pragma unroll 1
  for (int s = 0; s < nst; ++s) {
    if (s + 1 < nst) { asm volatile("s_waitcnt vmcnt(8)" ::: "memory"); }
    else             { asm volatile("s_waitcnt vmcnt(0)" ::: "memory"); }
    __builtin_amdgcn_s_barrier();        // buf[s&1] landed for all waves
    __builtin_amdgcn_sched_barrier(0);

    const int cur = s & 1;
    const int j0 = s * 64;
    const int kx = l5 & 15;

    // early V loads (T14): latency hides under the QK MFMAs below
    short8 vvA[8], vvB[8];
    {
      const u16* vp = vbase + j0;
#pragma unroll
      for (int n = 0; n < 4; ++n) {
#pragma unroll
        for (int cc = 0; cc < 2; ++cc) {
          vvA[n * 2 + cc] = *reinterpret_cast<const short8*>(vp + (size_t)(n * 32) * L_ + cc * 16);
          vvB[n * 2 + cc] = *reinterpret_cast<const short8*>(vp + (size_t)(n * 32) * L_ + 32 + cc * 16);
        }
      }
    }

    // subtile A: keys j0 + 0..31
    short8 kcA[8];
#pragma unroll
    for (int ss = 0; ss < 8; ++ss) {
      int phys = (2 * ss + hi) ^ kx;
      kcA[ss] = *reinterpret_cast<const short8*>(&Ks[cur][l5 * 128 + phys * 8]);
    }
    f32x16 Sa;
#pragma unroll
    for (int r = 0; r < 16; ++r) Sa[r] = 0.f;
#pragma unroll
    for (int ss = 0; ss < 8; ++ss)
      Sa = __builtin_amdgcn_mfma_f32_32x32x16_bf16(kcA[ss], qB[ss], Sa, 0, 0, 0);

    // subtile B: keys j0 + 32..63
    short8 kcB[8];
#pragma unroll
    for (int ss = 0; ss < 8; ++ss) {
      int phys = (2 * ss + hi) ^ kx;
      kcB[ss] = *reinterpret_cast<const short8*>(&Ks[cur][(32 + l5) * 128 + phys * 8]);
    }
    f32x16 Sb;
#pragma unroll
    for (int r = 0; r < 16; ++r) Sb[r] = 0.f;
#pragma unroll
    for (int ss = 0; ss < 8; ++ss)
      Sb = __builtin_amdgcn_mfma_f32_32x32x16_bf16(kcB[ss], qB[ss], Sb, 0, 0, 0);

    asm volatile("s_waitcnt lgkmcnt(0)" ::: "memory");
    __builtin_amdgcn_sched_barrier(0);
    __builtin_amdgcn_s_barrier();        // all waves done reading buf[cur]
    if (s + 2 < nst) stage(s + 2);       // overwrite buf[cur] for step s+2

    float sa[16], sb[16];
#pragma unroll
    for (int r = 0; r < 16; ++r) { sa[r] = Sa[r]; sb[r] = Sb[r]; }

    // causal masks
    if (j0 == q0) {
#pragma unroll
      for (int r = 0; r < 16; ++r) {
        int crow = (r & 3) + 8 * (r >> 2) + 4 * hi;
        if (crow > l5) sa[r] = -INFINITY;
        sb[r] = -INFINITY;
      }
    } else if (j0 + 32 == q0) {
#pragma unroll
      for (int r = 0; r < 16; ++r) {
        int crow = (r & 3) + 8 * (r >> 2) + 4 * hi;
        if (crow > l5) sb[r] = -INFINITY;
      }
    }

    // row max over 64 keys
    float t8[8], t4[4];
#pragma unroll
    for (int r = 0; r < 8; ++r) t8[r] = fmaxf(fmaxf(sa[2 * r], sa[2 * r + 1]),
                                              fmaxf(sb[2 * r], sb[2 * r + 1]));
#pragma unroll
    for (int r = 0; r < 4; ++r) t4[r] = fmaxf(t8[2 * r], t8[2 * r + 1]);
    float pmax = fmaxf(fmaxf(t4[0], t4[1]), fmaxf(t4[2], t4[3]));
    pmax = fmaxf(pmax, __shfl_xor(pmax, 32));

    // defer-max rescale (T13)
    if (__any(pmax > mrun + 8.0f)) {
      float mnew = fmaxf(mrun, pmax);
      float corr = __expf(mrun - mnew);
      mrun = mnew;
      lrun *= corr;
      if (hi == 0) cbufw[l5] = corr;
      float4 cr[4];
#pragma unroll
      for (int g = 0; g < 4; ++g)
        cr[g] = *reinterpret_cast<const float4*>(&cbufw[8 * g + 4 * hi]);
#pragma unroll
      for (int n = 0; n < 4; ++n)
#pragma unroll
        for (int r = 0; r < 16; ++r)
          O[n][r] *= (&cr[r >> 2].x)[r & 3];
    }

    // P = exp(S - m); per-half partial sum
    float pa_[16], pb_[16];
#pragma unroll
    for (int r = 0; r < 16; ++r) {
      pa_[r] = __expf(sa[r] - mrun);
      pb_[r] = __expf(sb[r] - mrun);
    }
#pragma unroll
    for (int r = 0; r < 8; ++r) t8[r] = (pa_[2 * r] + pa_[2 * r + 1]) +
                                        (pb_[2 * r] + pb_[2 * r + 1]);
#pragma unroll
    for (int r = 0; r < 4; ++r) t4[r] = t8[2 * r] + t8[2 * r + 1];
    lrun += (t4[0] + t4[1]) + (t4[2] + t4[3]);

    // pack P -> A-fragments (T12)
    short8 paA0, paA1, paB0, paB1;
    pack16(pa_, paA0, paA1);
    pack16(pb_, paB0, paB1);

    // O += P V
#pragma unroll
    for (int n = 0; n < 4; ++n) {
      O[n] = __builtin_amdgcn_mfma_f32_32x32x16_bf16(paA0, vvA[n * 2 + 0], O[n], 0, 0, 0);
      O[n] = __builtin_amdgcn_mfma_f32_32x32x16_bf16(paA1, vvA[n * 2 + 1], O[n], 0, 0, 0);
      O[n] = __builtin_amdgcn_mfma_f32_32x32x16_bf16(paB0, vvB[n * 2 + 0], O[n], 0, 0, 0);
      O[n] = __builtin_amdgcn_mfma_f32_32x32x16_bf16(paB1, vvB[n * 2 + 1], O[n], 0, 0, 0);
    }
  }

  u16* obase = ab + (size_t)(b * L_ + q0) * (HQ * DH) + h * DH;
  head_epilogue(O, lrun, l5, hi, cbufw, obase);
}

// ---------------------------------------------------------------------------
// launch
// ---------------------------------------------------------------------------
extern "C" void kernel_launch(void* const* d_in, const int* in_sizes, int n_in,
                              void* d_out, int out_size, void* d_ws, size_t ws_size,
                              hipStream_t stream) {
  const float* x  = (const float*)d_in[0];
  const float* wq = (const float*)d_in[1];
  const float* wk = (const float*)d_in[2];
  const float* wv = (const float*)d_in[3];
  const float* wo = (const float*)d_in[4];
  const float* bq = (const float*)d_in[5];
  const float* bk = (const float*)d_in[6];
  const float* bv = (const float*)d_in[7];
  float* out = (float*)d_out;

  const int M = B_ * L_;
  const int NQKV = HQ * DH + 2 * HKV * DH;  // 2560
  const size_t QN = (size_t)B_ * L_ * HQ * DH;
  const size_t KN = (size_t)B_ * L_ * HKV * DH;
  const size_t TN = (size_t)L_ * (DH / 2);

  float* ws = (float*)d_ws;
  float* ct   = ws;
  float* st   = ct + TN;
  float* bqkv = st + TN;
  u16* qkvb   = (u16*)(bqkv + 2560);        // bf16 QKV projection output
  u16* xb     = qkvb + (size_t)M * NQKV;
  u16* wqkvb  = xb + (size_t)M * E_;
  u16* Qbf    = wqkvb + (size_t)NQKV * E_;
  u16* Kbf    = Qbf + QN;
  u16* Vt     = Kbf + KN;
  u16* ab     = qkvb;   // alias: qkvb dead after rope/transpose
  u16* wob    = Qbf;    // alias: Qbf dead after attention

  const float scale = 0.08838834764831845f;

  rope_tab_kernel<<<(L_ * (DH / 2) + 255) / 256, 256, 0, stream>>>(ct, st);

  cvt_bf16_kernel<<<(int)(QN / 8 / 256), 256, 0, stream>>>(x, xb, (int)QN);
  cvt_bf16_kernel<<<(HQ * DH * E_) / 8 / 256, 256, 0, stream>>>(wq, wqkvb, HQ * DH * E_);
  cvt_bf16_kernel<<<(HKV * DH * E_) / 8 / 256, 256, 0, stream>>>(
      wk, wqkvb + (size_t)(HQ * DH) * E_, HKV * DH * E_);
  cvt_bf16_kernel<<<(HKV * DH * E_) / 8 / 256, 256, 0, stream>>>(
      wv, wqkvb + (size_t)(HQ * DH + HKV * DH) * E_, HKV * DH * E_);

  hipMemcpyAsync(bqkv, bq, (size_t)HQ * DH * 4, hipMemcpyDeviceToDevice, stream);
  hipMemcpyAsync(bqkv + HQ * DH, bk, (size_t)HKV * DH * 4, hipMemcpyDeviceToDevice, stream);
  hipMemcpyAsync(bqkv + HQ * DH + HKV * DH, bv, (size_t)HKV * DH * 4, hipMemcpyDeviceToDevice, stream);

  // fused QKV projection: [4096][2560]
  gemm_bf16_kernel<true><<<dim3(NQKV / GBN, M / GBM), 256, 0, stream>>>(
      xb, wqkvb, bqkv, qkvb, M, NQKV, E_);

  {
    int totq = B_ * L_ * HQ * 64;
    rope_convert_kernel<<<(totq + 255) / 256, 256, 0, stream>>>(
        qkvb, Qbf, ct, st, HQ, NQKV, 0, scale, totq);
    int totk = B_ * L_ * HKV * 64;
    rope_convert_kernel<<<(totk + 255) / 256, 256, 0, stream>>>(
        qkvb, Kbf, ct, st, HKV, NQKV, HQ * DH, 1.0f, totk);
  }
  transpose_v_kernel<<<dim3(L_ / 64, DH / 64, B_ * HKV), 256, 0, stream>>>(
      qkvb, Vt, NQKV, HQ * DH + HKV * DH);

  flash_attn_pipe_kernel<<<dim3(1024), 128, 0, stream>>>(Qbf, Kbf, Vt, ab);

  cvt_bf16_kernel<<<(E_ * E_) / 8 / 256, 256, 0, stream>>>(wo, wob, E_ * E_);
  gemm_bf16_kernel<false><<<dim3(E_ / GBN, M / GBM), 256, 0, stream>>>(
      ab, wob, nullptr, out, M, E_, E_);
}

// Round 18
// 224.204 us; speedup vs baseline: 1.1560x; 1.1560x over previous
//
#include <hip/hip_runtime.h>
#include <math.h>

#define B_ 2
#define L_ 2048
#define E_ 2048
#define HQ 16
#define HKV 2
#define DH 128

typedef unsigned short u16;
typedef unsigned int u32;
typedef __attribute__((ext_vector_type(8))) short short8;
typedef __attribute__((ext_vector_type(4))) float f32x4;
typedef __attribute__((ext_vector_type(16))) float f32x16;
typedef __attribute__((ext_vector_type(4))) u32 u32x4;

static __device__ __forceinline__ u16 f2bf(float f) {
  unsigned int u = __float_as_uint(f);
  unsigned int r = (u + 0x7fffu + ((u >> 16) & 1u)) >> 16;
  return (u16)r;
}
static __device__ __forceinline__ float bf2f(u16 v) {
  return __uint_as_float(((u32)v) << 16);
}

static __device__ __forceinline__ u32 cvt_pk_bf16(float lo, float hi) {
  u32 r;
  asm volatile("v_cvt_pk_bf16_f32 %0, %1, %2" : "=v"(r) : "v"(lo), "v"(hi));
  return r;
}
// swaps a's upper-half lanes with b's lower-half lanes (gfx950).
static __device__ __forceinline__ void permswap(u32& a, u32& b) {
  asm volatile("v_permlane32_swap_b32 %0, %1" : "+v"(a), "+v"(b));
}

#define GLB(p) ((const __attribute__((address_space(1))) void*)(p))
#define LDS(p) ((__attribute__((address_space(3))) void*)(p))

// ---------------------------------------------------------------------------
// fp32 -> bf16 convert
// ---------------------------------------------------------------------------
__global__ void cvt_bf16_kernel(const float* __restrict__ in,
                                u16* __restrict__ out, int n) {
  int i = (blockIdx.x * 256 + threadIdx.x) * 8;
  if (i >= n) return;
  float4 a = *reinterpret_cast<const float4*>(in + i);
  float4 b = *reinterpret_cast<const float4*>(in + i + 4);
  short8 r;
  r[0] = (short)f2bf(a.x); r[1] = (short)f2bf(a.y);
  r[2] = (short)f2bf(a.z); r[3] = (short)f2bf(a.w);
  r[4] = (short)f2bf(b.x); r[5] = (short)f2bf(b.y);
  r[6] = (short)f2bf(b.z); r[7] = (short)f2bf(b.w);
  *reinterpret_cast<short8*>(out + i) = r;
}

// ---------------------------------------------------------------------------
// RoPE table
// ---------------------------------------------------------------------------
__global__ void rope_tab_kernel(float* __restrict__ ctab, float* __restrict__ stab) {
  int idx = blockIdx.x * 256 + threadIdx.x;
  if (idx >= L_ * (DH / 2)) return;
  int pos = idx >> 6;
  int f = idx & 63;
  float inv_freq = powf(10000.0f, -(float)f * (1.0f / 64.0f));
  float ang = (float)pos * inv_freq;
  float s, c;
  sincosf(ang, &s, &c);
  ctab[idx] = c;
  stab[idx] = s;
}

// ---------------------------------------------------------------------------
// RoPE apply from bf16 fused-qkv buffer -> bf16 head-major buffer
// ---------------------------------------------------------------------------
__global__ void rope_convert_kernel(const u16* __restrict__ in,
                                    u16* __restrict__ outb,
                                    const float* __restrict__ ctab,
                                    const float* __restrict__ stab,
                                    int H, int rowStride, int colOff,
                                    float scale, int total) {
  int idx = blockIdx.x * 256 + threadIdx.x;
  if (idx >= total) return;
  int f = idx & 63;
  int row = idx >> 6;
  int h = row % H;
  int bl = row / H;
  int l = bl & (L_ - 1);
  size_t sbase = (size_t)bl * rowStride + colOff + (size_t)h * DH;
  size_t dbase = (size_t)bl * ((size_t)H * DH) + (size_t)h * DH;
  float x1 = bf2f(in[sbase + f]);
  float x2 = bf2f(in[sbase + 64 + f]);
  float c = ctab[l * 64 + f];
  float s = stab[l * 64 + f];
  outb[dbase + f]      = f2bf((x1 * c - x2 * s) * scale);
  outb[dbase + 64 + f] = f2bf((x2 * c + x1 * s) * scale);
}

// ---------------------------------------------------------------------------
// V transpose from bf16 qkv buffer: -> Vt[(b*HKV+kvh)*128+d][key]
// ---------------------------------------------------------------------------
__global__ __launch_bounds__(256) void transpose_v_kernel(
    const u16* __restrict__ v, u16* __restrict__ Vt,
    int rowStride, int colOff) {
  __shared__ u16 tile[64][68];
  const int k0 = blockIdx.x * 64;
  const int d0 = blockIdx.y * 64;
  const int bk = blockIdx.z;
  const int b = bk / HKV, kvh = bk % HKV;
#pragma unroll
  for (int i = 0; i < 4; ++i) {
    int key = i * 16 + (threadIdx.x >> 4);
    int d4 = (threadIdx.x & 15) * 4;
    *reinterpret_cast<ushort2*>(&tile[key][d4]) = *reinterpret_cast<const ushort2*>(
        &v[(size_t)(b * L_ + k0 + key) * rowStride + colOff + kvh * DH + d0 + d4]);
    *reinterpret_cast<ushort2*>(&tile[key][d4 + 2]) = *reinterpret_cast<const ushort2*>(
        &v[(size_t)(b * L_ + k0 + key) * rowStride + colOff + kvh * DH + d0 + d4 + 2]);
  }
  __syncthreads();
  const int d = threadIdx.x >> 2;
  const int kq = (threadIdx.x & 3) * 16;
  u16* orow = Vt + ((size_t)(bk * DH + d0 + d)) * L_ + k0 + kq;
#pragma unroll
  for (int j = 0; j < 16; ++j) orow[j] = tile[kq + j][d];
}

// ---------------------------------------------------------------------------
// bf16 MFMA GEMM: 128x128 tile, BK=64, single-buffer, 2x __syncthreads,
// XOR-slot LDS mapping (R14/R15-proven). 32 MFMAs per K-step.
// ---------------------------------------------------------------------------
#define GBM 128
#define GBN 128
#define GBK 64

template <bool BF16OUT>
__global__ __launch_bounds__(256) void gemm_bf16_kernel(
    const u16* __restrict__ A, const u16* __restrict__ W,
    const float* __restrict__ bias, void* __restrict__ Cv,
    int M, int N, int K)
{
  __shared__ u16 As[GBM * GBK];   // 16 KB
  __shared__ u16 Bs[GBN * GBK];   // 16 KB

  const int tid = threadIdx.x;
  const int wave = tid >> 6;
  const int lane = tid & 63;
  const int lr = lane & 15;
  const int lg = lane >> 4;
  const int bm = blockIdx.y * GBM;
  const int bn = blockIdx.x * GBN;
  const int wm = (wave >> 1) * 64;
  const int wn = (wave & 1) * 64;

  f32x4 acc[4][4];
#pragma unroll
  for (int i = 0; i < 4; ++i)
#pragma unroll
    for (int j = 0; j < 4; ++j) acc[i][j] = (f32x4){0.f, 0.f, 0.f, 0.f};

  const u16* gA[4];
  const u16* gB[4];
  u16* lA[4];
  u16* lB[4];
#pragma unroll
  for (int t = 0; t < 4; ++t) {
    int c = t * 256 + wave * 64 + lane;
    int row = c >> 3;
    int slog = (c & 7) ^ (row & 7);
    gA[t] = A + (size_t)(bm + row) * K + slog * 8;
    gB[t] = W + (size_t)(bn + row) * K + slog * 8;
    lA[t] = &As[(t * 256 + wave * 64) * 8];
    lB[t] = &Bs[(t * 256 + wave * 64) * 8];
  }

  const int fx = lr & 7;

  for (int k0 = 0; k0 < K; k0 += GBK) {
    __syncthreads();
#pragma unroll
    for (int t = 0; t < 4; ++t) {
      __builtin_amdgcn_global_load_lds(GLB(gA[t] + k0), LDS(lA[t]), 16, 0, 0);
      __builtin_amdgcn_global_load_lds(GLB(gB[t] + k0), LDS(lB[t]), 16, 0, 0);
    }
    __syncthreads();

#pragma unroll
    for (int kk = 0; kk < 2; ++kk) {
      short8 af[4], bf[4];
#pragma unroll
      for (int mi = 0; mi < 4; ++mi) {
        int row = wm + mi * 16 + lr;
        int slot = (kk * 4 + lg) ^ fx;
        af[mi] = *reinterpret_cast<const short8*>(&As[row * 64 + slot * 8]);
      }
#pragma unroll
      for (int ni = 0; ni < 4; ++ni) {
        int row = wn + ni * 16 + lr;
        int slot = (kk * 4 + lg) ^ fx;
        bf[ni] = *reinterpret_cast<const short8*>(&Bs[row * 64 + slot * 8]);
      }
#pragma unroll
      for (int mi = 0; mi < 4; ++mi)
#pragma unroll
        for (int ni = 0; ni < 4; ++ni)
          acc[mi][ni] = __builtin_amdgcn_mfma_f32_16x16x32_bf16(af[mi], bf[ni], acc[mi][ni], 0, 0, 0);
    }
  }

#pragma unroll
  for (int ni = 0; ni < 4; ++ni) {
    int col = bn + wn + ni * 16 + lr;
    float bv = (bias != nullptr) ? bias[col] : 0.f;
#pragma unroll
    for (int mi = 0; mi < 4; ++mi) {
#pragma unroll
      for (int r = 0; r < 4; ++r) {
        int row = bm + wm + mi * 16 + lg * 4 + r;
        float val = acc[mi][ni][r] + bv;
        if constexpr (BF16OUT)
          ((u16*)Cv)[(size_t)row * N + col] = f2bf(val);
        else
          ((float*)Cv)[(size_t)row * N + col] = val;
      }
    }
  }
}

// ---------------------------------------------------------------------------
// Flash attention (R16-proven config + T5 setprio): KVBLK=64, 4-wave blocks
// (4 heads), K+V LDS double-buffered, counted-vmcnt pipeline. Grid 512 = 2
// blocks/CU (blocks i, i+256 carry tiles 63-u and u).
// ---------------------------------------------------------------------------
__device__ __forceinline__ void pack16(const float p[16], short8& pa0, short8& pa1) {
  u32 w[8];
#pragma unroll
  for (int t = 0; t < 8; ++t) w[t] = cvt_pk_bf16(p[2 * t], p[2 * t + 1]);
  permswap(w[0], w[2]); permswap(w[1], w[3]);
  permswap(w[4], w[6]); permswap(w[5], w[7]);
  pa0 = __builtin_bit_cast(short8, (u32x4){w[0], w[1], w[2], w[3]});
  pa1 = __builtin_bit_cast(short8, (u32x4){w[4], w[5], w[6], w[7]});
}

__device__ __forceinline__ void head_epilogue(
    const f32x16 O[4], float lrun, int l5, int hi, float* cbufw,
    u16* __restrict__ obase)
{
  float ltot = lrun + __shfl_xor(lrun, 32);
  if (hi == 0) cbufw[l5] = ltot;
  float4 lv[4];
#pragma unroll
  for (int gg = 0; gg < 4; ++gg)
    lv[gg] = *reinterpret_cast<const float4*>(&cbufw[8 * gg + 4 * hi]);
#pragma unroll
  for (int r = 0; r < 16; ++r) {
    int crow = (r & 3) + 8 * (r >> 2) + 4 * hi;
    float inv = __builtin_amdgcn_rcpf((&lv[r >> 2].x)[r & 3]);
    u16* orow = obase + (size_t)crow * (HQ * DH) + l5;
#pragma unroll
    for (int n = 0; n < 4; ++n)
      orow[n * 32] = f2bf(O[n][r] * inv);
  }
}

__global__ __launch_bounds__(256, 2) void flash_attn_pipe_kernel(
    const u16* __restrict__ Qb, const u16* __restrict__ Kb,
    const u16* __restrict__ Vt, u16* __restrict__ ab)
{
  const int tid = threadIdx.x;
  const int wave = tid >> 6;
  const int lane = tid & 63;
  const int l5 = lane & 31;
  const int hi = lane >> 5;

  const int bid = blockIdx.x;
  const int half = bid >> 8;
  const int u = (bid >> 3) & 31;
  const int x = bid & 7;
  const int c = x >> 1;
  const int hh = x & 1;
  const int b = c >> 1, kvh = c & 1;
  const int h = kvh * 8 + hh * 4 + wave;
  const int t = half ? u : (63 - u);
  const int q0 = 32 * t;
  const int nst = (t + 2) >> 1;          // 64-key steps
  const int bk = b * HKV + kvh;

  __shared__ u16 Ks[2][64 * 128];   // 32 KB; 16 slots/row, phys = slot^(key&15)
  __shared__ u16 Vs[2][128 * 64];   // 32 KB; 8 slots/row,  phys = slot^(d&7)
  __shared__ __align__(16) float cbuf[4][32];
  float* cbufw = cbuf[wave];

  const u16* Kg = Kb + (size_t)(b * L_) * (HKV * DH) + kvh * DH;
  const u16* Vg = Vt + (size_t)(bk * DH) * L_;

  // 8 global_load_lds per thread per stage (4 K + 4 V chunks)
  auto stage = [&](int s) {
    const int buf = s & 1;
    const int j0 = s * 64;
#pragma unroll
    for (int q = 0; q < 4; ++q) {
      int cnk = q * 256 + tid;            // K chunk 0..1023
      int key = cnk >> 4, phys = cnk & 15;
      int slog = phys ^ (key & 15);
      const u16* src = Kg + (size_t)(j0 + key) * (HKV * DH) + slog * 8;
      __builtin_amdgcn_global_load_lds(GLB(src), LDS(&Ks[buf][(q * 256 + wave * 64) * 8]), 16, 0, 0);
    }
#pragma unroll
    for (int q = 0; q < 4; ++q) {
      int cnk = q * 256 + tid;            // V chunk 0..1023
      int d = cnk >> 3, phys = cnk & 7;
      int slog = phys ^ (d & 7);
      const u16* src = Vg + (size_t)d * L_ + j0 + slog * 8;
      __builtin_amdgcn_global_load_lds(GLB(src), LDS(&Vs[buf][(q * 256 + wave * 64) * 8]), 16, 0, 0);
    }
  };

  const u16* qrow = Qb + ((size_t)(b * L_ + q0 + l5)) * (HQ * DH) + h * DH + hi * 8;
  short8 qB[8];
#pragma unroll
  for (int ss = 0; ss < 8; ++ss)
    qB[ss] = *reinterpret_cast<const short8*>(qrow + ss * 16);

  f32x16 O[4];
#pragma unroll
  for (int n = 0; n < 4; ++n)
#pragma unroll
    for (int r = 0; r < 16; ++r) O[n][r] = 0.f;
  float mrun = -INFINITY, lrun = 0.f;

  stage(0);
  if (nst > 1) stage(1);

#pragma unroll 1
  for (int s = 0; s < nst; ++s) {
    if (s + 1 < nst) { asm volatile("s_waitcnt vmcnt(8)" ::: "memory"); }
    else             { asm volatile("s_waitcnt vmcnt(0)" ::: "memory"); }
    __builtin_amdgcn_s_barrier();          // buf[s&1] landed for all waves
    __builtin_amdgcn_sched_barrier(0);

    const int cur = s & 1;
    const int j0 = s * 64;
    const int kx = l5 & 15;

    // subtile A: keys j0 + 0..31
    short8 kcA[8], vvA[8];
#pragma unroll
    for (int ss = 0; ss < 8; ++ss) {
      int phys = (2 * ss + hi) ^ kx;
      kcA[ss] = *reinterpret_cast<const short8*>(&Ks[cur][l5 * 128 + phys * 8]);
    }
#pragma unroll
    for (int n = 0; n < 4; ++n) {
#pragma unroll
      for (int cc = 0; cc < 2; ++cc) {
        int d = n * 32 + l5;
        int phys = (cc * 2 + hi) ^ (d & 7);
        vvA[n * 2 + cc] = *reinterpret_cast<const short8*>(&Vs[cur][d * 64 + phys * 8]);
      }
    }
    f32x16 Sa;
#pragma unroll
    for (int r = 0; r < 16; ++r) Sa[r] = 0.f;
    __builtin_amdgcn_s_setprio(1);
#pragma unroll
    for (int ss = 0; ss < 8; ++ss)
      Sa = __builtin_amdgcn_mfma_f32_32x32x16_bf16(kcA[ss], qB[ss], Sa, 0, 0, 0);
    __builtin_amdgcn_s_setprio(0);

    // subtile B: keys j0 + 32..63
    short8 kcB[8], vvB[8];
#pragma unroll
    for (int ss = 0; ss < 8; ++ss) {
      int phys = (2 * ss + hi) ^ kx;
      kcB[ss] = *reinterpret_cast<const short8*>(&Ks[cur][(32 + l5) * 128 + phys * 8]);
    }
#pragma unroll
    for (int n = 0; n < 4; ++n) {
#pragma unroll
      for (int cc = 0; cc < 2; ++cc) {
        int d = n * 32 + l5;
        int phys = (4 + cc * 2 + hi) ^ (d & 7);
        vvB[n * 2 + cc] = *reinterpret_cast<const short8*>(&Vs[cur][d * 64 + phys * 8]);
      }
    }
    f32x16 Sb;
#pragma unroll
    for (int r = 0; r < 16; ++r) Sb[r] = 0.f;
    __builtin_amdgcn_s_setprio(1);
#pragma unroll
    for (int ss = 0; ss < 8; ++ss)
      Sb = __builtin_amdgcn_mfma_f32_32x32x16_bf16(kcB[ss], qB[ss], Sb, 0, 0, 0);
    __builtin_amdgcn_s_setprio(0);

    asm volatile("s_waitcnt lgkmcnt(0)" ::: "memory");
    __builtin_amdgcn_sched_barrier(0);
    __builtin_amdgcn_s_barrier();          // all waves done reading buf[cur]
    if (s + 2 < nst) stage(s + 2);         // overwrite buf[cur] for step s+2

    float sa[16], sb[16];
#pragma unroll
    for (int r = 0; r < 16; ++r) { sa[r] = Sa[r]; sb[r] = Sb[r]; }

    // causal masks
    if (j0 == q0) {
#pragma unroll
      for (int r = 0; r < 16; ++r) {
        int crow = (r & 3) + 8 * (r >> 2) + 4 * hi;
        if (crow > l5) sa[r] = -INFINITY;
        sb[r] = -INFINITY;                 // keys q0+32.. all beyond queries
      }
    } else if (j0 + 32 == q0) {
#pragma unroll
      for (int r = 0; r < 16; ++r) {
        int crow = (r & 3) + 8 * (r >> 2) + 4 * hi;
        if (crow > l5) sb[r] = -INFINITY;
      }
    }

    // row max over 64 keys: in-register trees + one cross-half exchange
    float t8[8], t4[4];
#pragma unroll
    for (int r = 0; r < 8; ++r) t8[r] = fmaxf(fmaxf(sa[2 * r], sa[2 * r + 1]),
                                              fmaxf(sb[2 * r], sb[2 * r + 1]));
#pragma unroll
    for (int r = 0; r < 4; ++r) t4[r] = fmaxf(t8[2 * r], t8[2 * r + 1]);
    float pmax = fmaxf(fmaxf(t4[0], t4[1]), fmaxf(t4[2], t4[3]));
    pmax = fmaxf(pmax, __shfl_xor(pmax, 32));

    // defer-max rescale (T13)
    if (__any(pmax > mrun + 8.0f)) {
      float mnew = fmaxf(mrun, pmax);
      float corr = __expf(mrun - mnew);
      mrun = mnew;
      lrun *= corr;
      if (hi == 0) cbufw[l5] = corr;
      float4 cr[4];
#pragma unroll
      for (int g = 0; g < 4; ++g)
        cr[g] = *reinterpret_cast<const float4*>(&cbufw[8 * g + 4 * hi]);
#pragma unroll
      for (int n = 0; n < 4; ++n)
#pragma unroll
        for (int r = 0; r < 16; ++r)
          O[n][r] *= (&cr[r >> 2].x)[r & 3];
    }

    // P = exp(S - m); per-half partial sum (cross-half merge at epilogue)
    float pa_[16], pb_[16];
#pragma unroll
    for (int r = 0; r < 16; ++r) {
      pa_[r] = __expf(sa[r] - mrun);
      pb_[r] = __expf(sb[r] - mrun);
    }
#pragma unroll
    for (int r = 0; r < 8; ++r) t8[r] = (pa_[2 * r] + pa_[2 * r + 1]) +
                                        (pb_[2 * r] + pb_[2 * r + 1]);
#pragma unroll
    for (int r = 0; r < 4; ++r) t4[r] = t8[2 * r] + t8[2 * r + 1];
    lrun += (t4[0] + t4[1]) + (t4[2] + t4[3]);

    // pack P -> A-fragments (T12, R5-validated per 16-value group)
    short8 paA0, paA1, paB0, paB1;
    pack16(pa_, paA0, paA1);
    pack16(pb_, paB0, paB1);

    // O += P V (4 k-slots of 16)
    __builtin_amdgcn_s_setprio(1);
#pragma unroll
    for (int n = 0; n < 4; ++n) {
      O[n] = __builtin_amdgcn_mfma_f32_32x32x16_bf16(paA0, vvA[n * 2 + 0], O[n], 0, 0, 0);
      O[n] = __builtin_amdgcn_mfma_f32_32x32x16_bf16(paA1, vvA[n * 2 + 1], O[n], 0, 0, 0);
      O[n] = __builtin_amdgcn_mfma_f32_32x32x16_bf16(paB0, vvB[n * 2 + 0], O[n], 0, 0, 0);
      O[n] = __builtin_amdgcn_mfma_f32_32x32x16_bf16(paB1, vvB[n * 2 + 1], O[n], 0, 0, 0);
    }
    __builtin_amdgcn_s_setprio(0);
  }

  u16* obase = ab + (size_t)(b * L_ + q0) * (HQ * DH) + h * DH;
  head_epilogue(O, lrun, l5, hi, cbufw, obase);
}

// ---------------------------------------------------------------------------
// launch
// ---------------------------------------------------------------------------
extern "C" void kernel_launch(void* const* d_in, const int* in_sizes, int n_in,
                              void* d_out, int out_size, void* d_ws, size_t ws_size,
                              hipStream_t stream) {
  const float* x  = (const float*)d_in[0];
  const float* wq = (const float*)d_in[1];
  const float* wk = (const float*)d_in[2];
  const float* wv = (const float*)d_in[3];
  const float* wo = (const float*)d_in[4];
  const float* bq = (const float*)d_in[5];
  const float* bk = (const float*)d_in[6];
  const float* bv = (const float*)d_in[7];
  float* out = (float*)d_out;

  const int M = B_ * L_;
  const int NQKV = HQ * DH + 2 * HKV * DH;  // 2560
  const size_t QN = (size_t)B_ * L_ * HQ * DH;
  const size_t KN = (size_t)B_ * L_ * HKV * DH;
  const size_t TN = (size_t)L_ * (DH / 2);

  float* ws = (float*)d_ws;
  float* ct   = ws;
  float* st   = ct + TN;
  float* bqkv = st + TN;
  u16* qkvb   = (u16*)(bqkv + 2560);        // bf16 QKV projection output
  u16* xb     = qkvb + (size_t)M * NQKV;
  u16* wqkvb  = xb + (size_t)M * E_;
  u16* Qbf    = wqkvb + (size_t)NQKV * E_;
  u16* Kbf    = Qbf + QN;
  u16* Vt     = Kbf + KN;
  u16* ab     = qkvb;   // alias: qkvb dead after rope/transpose
  u16* wob    = Qbf;    // alias: Qbf dead after attention

  const float scale = 0.08838834764831845f;

  rope_tab_kernel<<<(L_ * (DH / 2) + 255) / 256, 256, 0, stream>>>(ct, st);

  cvt_bf16_kernel<<<(int)(QN / 8 / 256), 256, 0, stream>>>(x, xb, (int)QN);
  cvt_bf16_kernel<<<(HQ * DH * E_) / 8 / 256, 256, 0, stream>>>(wq, wqkvb, HQ * DH * E_);
  cvt_bf16_kernel<<<(HKV * DH * E_) / 8 / 256, 256, 0, stream>>>(
      wk, wqkvb + (size_t)(HQ * DH) * E_, HKV * DH * E_);
  cvt_bf16_kernel<<<(HKV * DH * E_) / 8 / 256, 256, 0, stream>>>(
      wv, wqkvb + (size_t)(HQ * DH + HKV * DH) * E_, HKV * DH * E_);

  hipMemcpyAsync(bqkv, bq, (size_t)HQ * DH * 4, hipMemcpyDeviceToDevice, stream);
  hipMemcpyAsync(bqkv + HQ * DH, bk, (size_t)HKV * DH * 4, hipMemcpyDeviceToDevice, stream);
  hipMemcpyAsync(bqkv + HQ * DH + HKV * DH, bv, (size_t)HKV * DH * 4, hipMemcpyDeviceToDevice, stream);

  // fused QKV projection: [4096][2560]
  gemm_bf16_kernel<true><<<dim3(NQKV / GBN, M / GBM), 256, 0, stream>>>(
      xb, wqkvb, bqkv, qkvb, M, NQKV, E_);

  {
    int totq = B_ * L_ * HQ * 64;
    rope_convert_kernel<<<(totq + 255) / 256, 256, 0, stream>>>(
        qkvb, Qbf, ct, st, HQ, NQKV, 0, scale, totq);
    int totk = B_ * L_ * HKV * 64;
    rope_convert_kernel<<<(totk + 255) / 256, 256, 0, stream>>>(
        qkvb, Kbf, ct, st, HKV, NQKV, HQ * DH, 1.0f, totk);
  }
  transpose_v_kernel<<<dim3(L_ / 64, DH / 64, B_ * HKV), 256, 0, stream>>>(
      qkvb, Vt, NQKV, HQ * DH + HKV * DH);

  flash_attn_pipe_kernel<<<dim3(512), 256, 0, stream>>>(Qbf, Kbf, Vt, ab);

  cvt_bf16_kernel<<<(E_ * E_) / 8 / 256, 256, 0, stream>>>(wo, wob, E_ * E_);
  gemm_bf16_kernel<false><<<dim3(E_ / GBN, M / GBM), 256, 0, stream>>>(
      ab, wob, nullptr, out, M, E_, E_);
}

// Round 19
// 208.085 us; speedup vs baseline: 1.2455x; 1.0775x over previous
//
#include <hip/hip_runtime.h>
#include <math.h>

#define B_ 2
#define L_ 2048
#define E_ 2048
#define HQ 16
#define HKV 2
#define DH 128

typedef unsigned short u16;
typedef unsigned int u32;
typedef __attribute__((ext_vector_type(8))) short short8;
typedef __attribute__((ext_vector_type(4))) float f32x4;
typedef __attribute__((ext_vector_type(16))) float f32x16;
typedef __attribute__((ext_vector_type(4))) u32 u32x4;

static __device__ __forceinline__ u16 f2bf(float f) {
  unsigned int u = __float_as_uint(f);
  unsigned int r = (u + 0x7fffu + ((u >> 16) & 1u)) >> 16;
  return (u16)r;
}
static __device__ __forceinline__ float bf2f(u16 v) {
  return __uint_as_float(((u32)v) << 16);
}

static __device__ __forceinline__ u32 cvt_pk_bf16(float lo, float hi) {
  u32 r;
  asm volatile("v_cvt_pk_bf16_f32 %0, %1, %2" : "=v"(r) : "v"(lo), "v"(hi));
  return r;
}
// swaps a's upper-half lanes with b's lower-half lanes (gfx950).
static __device__ __forceinline__ void permswap(u32& a, u32& b) {
  asm volatile("v_permlane32_swap_b32 %0, %1" : "+v"(a), "+v"(b));
}

#define GLB(p) ((const __attribute__((address_space(1))) void*)(p))
#define LDS(p) ((__attribute__((address_space(3))) void*)(p))

// ---------------------------------------------------------------------------
// fp32 -> bf16 convert
// ---------------------------------------------------------------------------
__global__ void cvt_bf16_kernel(const float* __restrict__ in,
                                u16* __restrict__ out, int n) {
  int i = (blockIdx.x * 256 + threadIdx.x) * 8;
  if (i >= n) return;
  float4 a = *reinterpret_cast<const float4*>(in + i);
  float4 b = *reinterpret_cast<const float4*>(in + i + 4);
  short8 r;
  r[0] = (short)f2bf(a.x); r[1] = (short)f2bf(a.y);
  r[2] = (short)f2bf(a.z); r[3] = (short)f2bf(a.w);
  r[4] = (short)f2bf(b.x); r[5] = (short)f2bf(b.y);
  r[6] = (short)f2bf(b.z); r[7] = (short)f2bf(b.w);
  *reinterpret_cast<short8*>(out + i) = r;
}

// ---------------------------------------------------------------------------
// RoPE table
// ---------------------------------------------------------------------------
__global__ void rope_tab_kernel(float* __restrict__ ctab, float* __restrict__ stab) {
  int idx = blockIdx.x * 256 + threadIdx.x;
  if (idx >= L_ * (DH / 2)) return;
  int pos = idx >> 6;
  int f = idx & 63;
  float inv_freq = powf(10000.0f, -(float)f * (1.0f / 64.0f));
  float ang = (float)pos * inv_freq;
  float s, c;
  sincosf(ang, &s, &c);
  ctab[idx] = c;
  stab[idx] = s;
}

// ---------------------------------------------------------------------------
// RoPE apply from bf16 fused-qkv buffer -> bf16 head-major buffer
// ---------------------------------------------------------------------------
__global__ void rope_convert_kernel(const u16* __restrict__ in,
                                    u16* __restrict__ outb,
                                    const float* __restrict__ ctab,
                                    const float* __restrict__ stab,
                                    int H, int rowStride, int colOff,
                                    float scale, int total) {
  int idx = blockIdx.x * 256 + threadIdx.x;
  if (idx >= total) return;
  int f = idx & 63;
  int row = idx >> 6;
  int h = row % H;
  int bl = row / H;
  int l = bl & (L_ - 1);
  size_t sbase = (size_t)bl * rowStride + colOff + (size_t)h * DH;
  size_t dbase = (size_t)bl * ((size_t)H * DH) + (size_t)h * DH;
  float x1 = bf2f(in[sbase + f]);
  float x2 = bf2f(in[sbase + 64 + f]);
  float c = ctab[l * 64 + f];
  float s = stab[l * 64 + f];
  outb[dbase + f]      = f2bf((x1 * c - x2 * s) * scale);
  outb[dbase + 64 + f] = f2bf((x2 * c + x1 * s) * scale);
}

// ---------------------------------------------------------------------------
// V transpose from bf16 qkv buffer: -> Vt[(b*HKV+kvh)*128+d][key]
// ---------------------------------------------------------------------------
__global__ __launch_bounds__(256) void transpose_v_kernel(
    const u16* __restrict__ v, u16* __restrict__ Vt,
    int rowStride, int colOff) {
  __shared__ u16 tile[64][68];
  const int k0 = blockIdx.x * 64;
  const int d0 = blockIdx.y * 64;
  const int bk = blockIdx.z;
  const int b = bk / HKV, kvh = bk % HKV;
#pragma unroll
  for (int i = 0; i < 4; ++i) {
    int key = i * 16 + (threadIdx.x >> 4);
    int d4 = (threadIdx.x & 15) * 4;
    *reinterpret_cast<ushort2*>(&tile[key][d4]) = *reinterpret_cast<const ushort2*>(
        &v[(size_t)(b * L_ + k0 + key) * rowStride + colOff + kvh * DH + d0 + d4]);
    *reinterpret_cast<ushort2*>(&tile[key][d4 + 2]) = *reinterpret_cast<const ushort2*>(
        &v[(size_t)(b * L_ + k0 + key) * rowStride + colOff + kvh * DH + d0 + d4 + 2]);
  }
  __syncthreads();
  const int d = threadIdx.x >> 2;
  const int kq = (threadIdx.x & 3) * 16;
  u16* orow = Vt + ((size_t)(bk * DH + d0 + d)) * L_ + k0 + kq;
#pragma unroll
  for (int j = 0; j < 16; ++j) orow[j] = tile[kq + j][d];
}

// ---------------------------------------------------------------------------
// bf16 MFMA GEMM: 128x128 tile, BK=64, single-buffer, 2x __syncthreads,
// XOR-slot LDS mapping (R14/R15-proven). 32 MFMAs per K-step.
// ---------------------------------------------------------------------------
#define GBM 128
#define GBN 128
#define GBK 64

template <bool BF16OUT>
__global__ __launch_bounds__(256) void gemm_bf16_kernel(
    const u16* __restrict__ A, const u16* __restrict__ W,
    const float* __restrict__ bias, void* __restrict__ Cv,
    int M, int N, int K)
{
  __shared__ u16 As[GBM * GBK];   // 16 KB
  __shared__ u16 Bs[GBN * GBK];   // 16 KB

  const int tid = threadIdx.x;
  const int wave = tid >> 6;
  const int lane = tid & 63;
  const int lr = lane & 15;
  const int lg = lane >> 4;
  const int bm = blockIdx.y * GBM;
  const int bn = blockIdx.x * GBN;
  const int wm = (wave >> 1) * 64;
  const int wn = (wave & 1) * 64;

  f32x4 acc[4][4];
#pragma unroll
  for (int i = 0; i < 4; ++i)
#pragma unroll
    for (int j = 0; j < 4; ++j) acc[i][j] = (f32x4){0.f, 0.f, 0.f, 0.f};

  const u16* gA[4];
  const u16* gB[4];
  u16* lA[4];
  u16* lB[4];
#pragma unroll
  for (int t = 0; t < 4; ++t) {
    int c = t * 256 + wave * 64 + lane;
    int row = c >> 3;
    int slog = (c & 7) ^ (row & 7);
    gA[t] = A + (size_t)(bm + row) * K + slog * 8;
    gB[t] = W + (size_t)(bn + row) * K + slog * 8;
    lA[t] = &As[(t * 256 + wave * 64) * 8];
    lB[t] = &Bs[(t * 256 + wave * 64) * 8];
  }

  const int fx = lr & 7;

  for (int k0 = 0; k0 < K; k0 += GBK) {
    __syncthreads();
#pragma unroll
    for (int t = 0; t < 4; ++t) {
      __builtin_amdgcn_global_load_lds(GLB(gA[t] + k0), LDS(lA[t]), 16, 0, 0);
      __builtin_amdgcn_global_load_lds(GLB(gB[t] + k0), LDS(lB[t]), 16, 0, 0);
    }
    __syncthreads();

#pragma unroll
    for (int kk = 0; kk < 2; ++kk) {
      short8 af[4], bf[4];
#pragma unroll
      for (int mi = 0; mi < 4; ++mi) {
        int row = wm + mi * 16 + lr;
        int slot = (kk * 4 + lg) ^ fx;
        af[mi] = *reinterpret_cast<const short8*>(&As[row * 64 + slot * 8]);
      }
#pragma unroll
      for (int ni = 0; ni < 4; ++ni) {
        int row = wn + ni * 16 + lr;
        int slot = (kk * 4 + lg) ^ fx;
        bf[ni] = *reinterpret_cast<const short8*>(&Bs[row * 64 + slot * 8]);
      }
#pragma unroll
      for (int mi = 0; mi < 4; ++mi)
#pragma unroll
        for (int ni = 0; ni < 4; ++ni)
          acc[mi][ni] = __builtin_amdgcn_mfma_f32_16x16x32_bf16(af[mi], bf[ni], acc[mi][ni], 0, 0, 0);
    }
  }

#pragma unroll
  for (int ni = 0; ni < 4; ++ni) {
    int col = bn + wn + ni * 16 + lr;
    float bv = (bias != nullptr) ? bias[col] : 0.f;
#pragma unroll
    for (int mi = 0; mi < 4; ++mi) {
#pragma unroll
      for (int r = 0; r < 4; ++r) {
        int row = bm + wm + mi * 16 + lg * 4 + r;
        float val = acc[mi][ni][r] + bv;
        if constexpr (BF16OUT)
          ((u16*)Cv)[(size_t)row * N + col] = f2bf(val);
        else
          ((float*)Cv)[(size_t)row * N + col] = val;
      }
    }
  }
}

// ---------------------------------------------------------------------------
// Flash attention (R16-proven config, NO setprio): KVBLK=64, 4-wave blocks
// (4 heads), K+V LDS double-buffered, counted-vmcnt pipeline. Grid 512 = 2
// blocks/CU (blocks i, i+256 carry tiles 63-u and u).
// ---------------------------------------------------------------------------
__device__ __forceinline__ void pack16(const float p[16], short8& pa0, short8& pa1) {
  u32 w[8];
#pragma unroll
  for (int t = 0; t < 8; ++t) w[t] = cvt_pk_bf16(p[2 * t], p[2 * t + 1]);
  permswap(w[0], w[2]); permswap(w[1], w[3]);
  permswap(w[4], w[6]); permswap(w[5], w[7]);
  pa0 = __builtin_bit_cast(short8, (u32x4){w[0], w[1], w[2], w[3]});
  pa1 = __builtin_bit_cast(short8, (u32x4){w[4], w[5], w[6], w[7]});
}

__device__ __forceinline__ void head_epilogue(
    const f32x16 O[4], float lrun, int l5, int hi, float* cbufw,
    u16* __restrict__ obase)
{
  float ltot = lrun + __shfl_xor(lrun, 32);
  if (hi == 0) cbufw[l5] = ltot;
  float4 lv[4];
#pragma unroll
  for (int gg = 0; gg < 4; ++gg)
    lv[gg] = *reinterpret_cast<const float4*>(&cbufw[8 * gg + 4 * hi]);
#pragma unroll
  for (int r = 0; r < 16; ++r) {
    int crow = (r & 3) + 8 * (r >> 2) + 4 * hi;
    float inv = __builtin_amdgcn_rcpf((&lv[r >> 2].x)[r & 3]);
    u16* orow = obase + (size_t)crow * (HQ * DH) + l5;
#pragma unroll
    for (int n = 0; n < 4; ++n)
      orow[n * 32] = f2bf(O[n][r] * inv);
  }
}

__global__ __launch_bounds__(256, 2) void flash_attn_pipe_kernel(
    const u16* __restrict__ Qb, const u16* __restrict__ Kb,
    const u16* __restrict__ Vt, u16* __restrict__ ab)
{
  const int tid = threadIdx.x;
  const int wave = tid >> 6;
  const int lane = tid & 63;
  const int l5 = lane & 31;
  const int hi = lane >> 5;

  const int bid = blockIdx.x;
  const int half = bid >> 8;
  const int u = (bid >> 3) & 31;
  const int x = bid & 7;
  const int c = x >> 1;
  const int hh = x & 1;
  const int b = c >> 1, kvh = c & 1;
  const int h = kvh * 8 + hh * 4 + wave;
  const int t = half ? u : (63 - u);
  const int q0 = 32 * t;
  const int nst = (t + 2) >> 1;          // 64-key steps
  const int bk = b * HKV + kvh;

  __shared__ u16 Ks[2][64 * 128];   // 32 KB; 16 slots/row, phys = slot^(key&15)
  __shared__ u16 Vs[2][128 * 64];   // 32 KB; 8 slots/row,  phys = slot^(d&7)
  __shared__ __align__(16) float cbuf[4][32];
  float* cbufw = cbuf[wave];

  const u16* Kg = Kb + (size_t)(b * L_) * (HKV * DH) + kvh * DH;
  const u16* Vg = Vt + (size_t)(bk * DH) * L_;

  // 8 global_load_lds per thread per stage (4 K + 4 V chunks)
  auto stage = [&](int s) {
    const int buf = s & 1;
    const int j0 = s * 64;
#pragma unroll
    for (int q = 0; q < 4; ++q) {
      int cnk = q * 256 + tid;            // K chunk 0..1023
      int key = cnk >> 4, phys = cnk & 15;
      int slog = phys ^ (key & 15);
      const u16* src = Kg + (size_t)(j0 + key) * (HKV * DH) + slog * 8;
      __builtin_amdgcn_global_load_lds(GLB(src), LDS(&Ks[buf][(q * 256 + wave * 64) * 8]), 16, 0, 0);
    }
#pragma unroll
    for (int q = 0; q < 4; ++q) {
      int cnk = q * 256 + tid;            // V chunk 0..1023
      int d = cnk >> 3, phys = cnk & 7;
      int slog = phys ^ (d & 7);
      const u16* src = Vg + (size_t)d * L_ + j0 + slog * 8;
      __builtin_amdgcn_global_load_lds(GLB(src), LDS(&Vs[buf][(q * 256 + wave * 64) * 8]), 16, 0, 0);
    }
  };

  const u16* qrow = Qb + ((size_t)(b * L_ + q0 + l5)) * (HQ * DH) + h * DH + hi * 8;
  short8 qB[8];
#pragma unroll
  for (int ss = 0; ss < 8; ++ss)
    qB[ss] = *reinterpret_cast<const short8*>(qrow + ss * 16);

  f32x16 O[4];
#pragma unroll
  for (int n = 0; n < 4; ++n)
#pragma unroll
    for (int r = 0; r < 16; ++r) O[n][r] = 0.f;
  float mrun = -INFINITY, lrun = 0.f;

  stage(0);
  if (nst > 1) stage(1);

#pragma unroll 1
  for (int s = 0; s < nst; ++s) {
    if (s + 1 < nst) { asm volatile("s_waitcnt vmcnt(8)" ::: "memory"); }
    else             { asm volatile("s_waitcnt vmcnt(0)" ::: "memory"); }
    __builtin_amdgcn_s_barrier();          // buf[s&1] landed for all waves
    __builtin_amdgcn_sched_barrier(0);

    const int cur = s & 1;
    const int j0 = s * 64;
    const int kx = l5 & 15;

    // subtile A: keys j0 + 0..31
    short8 kcA[8], vvA[8];
#pragma unroll
    for (int ss = 0; ss < 8; ++ss) {
      int phys = (2 * ss + hi) ^ kx;
      kcA[ss] = *reinterpret_cast<const short8*>(&Ks[cur][l5 * 128 + phys * 8]);
    }
#pragma unroll
    for (int n = 0; n < 4; ++n) {
#pragma unroll
      for (int cc = 0; cc < 2; ++cc) {
        int d = n * 32 + l5;
        int phys = (cc * 2 + hi) ^ (d & 7);
        vvA[n * 2 + cc] = *reinterpret_cast<const short8*>(&Vs[cur][d * 64 + phys * 8]);
      }
    }
    f32x16 Sa;
#pragma unroll
    for (int r = 0; r < 16; ++r) Sa[r] = 0.f;
#pragma unroll
    for (int ss = 0; ss < 8; ++ss)
      Sa = __builtin_amdgcn_mfma_f32_32x32x16_bf16(kcA[ss], qB[ss], Sa, 0, 0, 0);

    // subtile B: keys j0 + 32..63
    short8 kcB[8], vvB[8];
#pragma unroll
    for (int ss = 0; ss < 8; ++ss) {
      int phys = (2 * ss + hi) ^ kx;
      kcB[ss] = *reinterpret_cast<const short8*>(&Ks[cur][(32 + l5) * 128 + phys * 8]);
    }
#pragma unroll
    for (int n = 0; n < 4; ++n) {
#pragma unroll
      for (int cc = 0; cc < 2; ++cc) {
        int d = n * 32 + l5;
        int phys = (4 + cc * 2 + hi) ^ (d & 7);
        vvB[n * 2 + cc] = *reinterpret_cast<const short8*>(&Vs[cur][d * 64 + phys * 8]);
      }
    }
    f32x16 Sb;
#pragma unroll
    for (int r = 0; r < 16; ++r) Sb[r] = 0.f;
#pragma unroll
    for (int ss = 0; ss < 8; ++ss)
      Sb = __builtin_amdgcn_mfma_f32_32x32x16_bf16(kcB[ss], qB[ss], Sb, 0, 0, 0);

    asm volatile("s_waitcnt lgkmcnt(0)" ::: "memory");
    __builtin_amdgcn_sched_barrier(0);
    __builtin_amdgcn_s_barrier();          // all waves done reading buf[cur]
    if (s + 2 < nst) stage(s + 2);         // overwrite buf[cur] for step s+2

    float sa[16], sb[16];
#pragma unroll
    for (int r = 0; r < 16; ++r) { sa[r] = Sa[r]; sb[r] = Sb[r]; }

    // causal masks
    if (j0 == q0) {
#pragma unroll
      for (int r = 0; r < 16; ++r) {
        int crow = (r & 3) + 8 * (r >> 2) + 4 * hi;
        if (crow > l5) sa[r] = -INFINITY;
        sb[r] = -INFINITY;                 // keys q0+32.. all beyond queries
      }
    } else if (j0 + 32 == q0) {
#pragma unroll
      for (int r = 0; r < 16; ++r) {
        int crow = (r & 3) + 8 * (r >> 2) + 4 * hi;
        if (crow > l5) sb[r] = -INFINITY;
      }
    }

    // row max over 64 keys: in-register trees + one cross-half exchange
    float t8[8], t4[4];
#pragma unroll
    for (int r = 0; r < 8; ++r) t8[r] = fmaxf(fmaxf(sa[2 * r], sa[2 * r + 1]),
                                              fmaxf(sb[2 * r], sb[2 * r + 1]));
#pragma unroll
    for (int r = 0; r < 4; ++r) t4[r] = fmaxf(t8[2 * r], t8[2 * r + 1]);
    float pmax = fmaxf(fmaxf(t4[0], t4[1]), fmaxf(t4[2], t4[3]));
    pmax = fmaxf(pmax, __shfl_xor(pmax, 32));

    // defer-max rescale (T13)
    if (__any(pmax > mrun + 8.0f)) {
      float mnew = fmaxf(mrun, pmax);
      float corr = __expf(mrun - mnew);
      mrun = mnew;
      lrun *= corr;
      if (hi == 0) cbufw[l5] = corr;
      float4 cr[4];
#pragma unroll
      for (int g = 0; g < 4; ++g)
        cr[g] = *reinterpret_cast<const float4*>(&cbufw[8 * g + 4 * hi]);
#pragma unroll
      for (int n = 0; n < 4; ++n)
#pragma unroll
        for (int r = 0; r < 16; ++r)
          O[n][r] *= (&cr[r >> 2].x)[r & 3];
    }

    // P = exp(S - m); per-half partial sum (cross-half merge at epilogue)
    float pa_[16], pb_[16];
#pragma unroll
    for (int r = 0; r < 16; ++r) {
      pa_[r] = __expf(sa[r] - mrun);
      pb_[r] = __expf(sb[r] - mrun);
    }
#pragma unroll
    for (int r = 0; r < 8; ++r) t8[r] = (pa_[2 * r] + pa_[2 * r + 1]) +
                                        (pb_[2 * r] + pb_[2 * r + 1]);
#pragma unroll
    for (int r = 0; r < 4; ++r) t4[r] = t8[2 * r] + t8[2 * r + 1];
    lrun += (t4[0] + t4[1]) + (t4[2] + t4[3]);

    // pack P -> A-fragments (T12, R5-validated per 16-value group)
    short8 paA0, paA1, paB0, paB1;
    pack16(pa_, paA0, paA1);
    pack16(pb_, paB0, paB1);

    // O += P V (4 k-slots of 16)
#pragma unroll
    for (int n = 0; n < 4; ++n) {
      O[n] = __builtin_amdgcn_mfma_f32_32x32x16_bf16(paA0, vvA[n * 2 + 0], O[n], 0, 0, 0);
      O[n] = __builtin_amdgcn_mfma_f32_32x32x16_bf16(paA1, vvA[n * 2 + 1], O[n], 0, 0, 0);
      O[n] = __builtin_amdgcn_mfma_f32_32x32x16_bf16(paB0, vvB[n * 2 + 0], O[n], 0, 0, 0);
      O[n] = __builtin_amdgcn_mfma_f32_32x32x16_bf16(paB1, vvB[n * 2 + 1], O[n], 0, 0, 0);
    }
  }

  u16* obase = ab + (size_t)(b * L_ + q0) * (HQ * DH) + h * DH;
  head_epilogue(O, lrun, l5, hi, cbufw, obase);
}

// ---------------------------------------------------------------------------
// launch
// ---------------------------------------------------------------------------
extern "C" void kernel_launch(void* const* d_in, const int* in_sizes, int n_in,
                              void* d_out, int out_size, void* d_ws, size_t ws_size,
                              hipStream_t stream) {
  const float* x  = (const float*)d_in[0];
  const float* wq = (const float*)d_in[1];
  const float* wk = (const float*)d_in[2];
  const float* wv = (const float*)d_in[3];
  const float* wo = (const float*)d_in[4];
  const float* bq = (const float*)d_in[5];
  const float* bk = (const float*)d_in[6];
  const float* bv = (const float*)d_in[7];
  float* out = (float*)d_out;

  const int M = B_ * L_;
  const int NQKV = HQ * DH + 2 * HKV * DH;  // 2560
  const size_t QN = (size_t)B_ * L_ * HQ * DH;
  const size_t KN = (size_t)B_ * L_ * HKV * DH;
  const size_t TN = (size_t)L_ * (DH / 2);

  float* ws = (float*)d_ws;
  float* ct   = ws;
  float* st   = ct + TN;
  float* bqkv = st + TN;
  u16* qkvb   = (u16*)(bqkv + 2560);        // bf16 QKV projection output
  u16* xb     = qkvb + (size_t)M * NQKV;
  u16* wqkvb  = xb + (size_t)M * E_;
  u16* Qbf    = wqkvb + (size_t)NQKV * E_;
  u16* Kbf    = Qbf + QN;
  u16* Vt     = Kbf + KN;
  u16* ab     = qkvb;   // alias: qkvb dead after rope/transpose
  u16* wob    = Qbf;    // alias: Qbf dead after attention

  const float scale = 0.08838834764831845f;

  rope_tab_kernel<<<(L_ * (DH / 2) + 255) / 256, 256, 0, stream>>>(ct, st);

  cvt_bf16_kernel<<<(int)(QN / 8 / 256), 256, 0, stream>>>(x, xb, (int)QN);
  cvt_bf16_kernel<<<(HQ * DH * E_) / 8 / 256, 256, 0, stream>>>(wq, wqkvb, HQ * DH * E_);
  cvt_bf16_kernel<<<(HKV * DH * E_) / 8 / 256, 256, 0, stream>>>(
      wk, wqkvb + (size_t)(HQ * DH) * E_, HKV * DH * E_);
  cvt_bf16_kernel<<<(HKV * DH * E_) / 8 / 256, 256, 0, stream>>>(
      wv, wqkvb + (size_t)(HQ * DH + HKV * DH) * E_, HKV * DH * E_);

  hipMemcpyAsync(bqkv, bq, (size_t)HQ * DH * 4, hipMemcpyDeviceToDevice, stream);
  hipMemcpyAsync(bqkv + HQ * DH, bk, (size_t)HKV * DH * 4, hipMemcpyDeviceToDevice, stream);
  hipMemcpyAsync(bqkv + HQ * DH + HKV * DH, bv, (size_t)HKV * DH * 4, hipMemcpyDeviceToDevice, stream);

  // fused QKV projection: [4096][2560]
  gemm_bf16_kernel<true><<<dim3(NQKV / GBN, M / GBM), 256, 0, stream>>>(
      xb, wqkvb, bqkv, qkvb, M, NQKV, E_);

  {
    int totq = B_ * L_ * HQ * 64;
    rope_convert_kernel<<<(totq + 255) / 256, 256, 0, stream>>>(
        qkvb, Qbf, ct, st, HQ, NQKV, 0, scale, totq);
    int totk = B_ * L_ * HKV * 64;
    rope_convert_kernel<<<(totk + 255) / 256, 256, 0, stream>>>(
        qkvb, Kbf, ct, st, HKV, NQKV, HQ * DH, 1.0f, totk);
  }
  transpose_v_kernel<<<dim3(L_ / 64, DH / 64, B_ * HKV), 256, 0, stream>>>(
      qkvb, Vt, NQKV, HQ * DH + HKV * DH);

  flash_attn_pipe_kernel<<<dim3(512), 256, 0, stream>>>(Qbf, Kbf, Vt, ab);

  cvt_bf16_kernel<<<(E_ * E_) / 8 / 256, 256, 0, stream>>>(wo, wob, E_ * E_);
  gemm_bf16_kernel<false><<<dim3(E_ / GBN, M / GBM), 256, 0, stream>>>(
      ab, wob, nullptr, out, M, E_, E_);
}

// Round 20
// 193.175 us; speedup vs baseline: 1.3417x; 1.0772x over previous
//
#include <hip/hip_runtime.h>
#include <math.h>

#define B_ 2
#define L_ 2048
#define E_ 2048
#define HQ 16
#define HKV 2
#define DH 128
#define NQKV_ 2560

typedef unsigned short u16;
typedef unsigned int u32;
typedef __attribute__((ext_vector_type(8))) short short8;
typedef __attribute__((ext_vector_type(4))) float f32x4;
typedef __attribute__((ext_vector_type(16))) float f32x16;
typedef __attribute__((ext_vector_type(4))) u32 u32x4;

static __device__ __forceinline__ u16 f2bf(float f) {
  unsigned int u = __float_as_uint(f);
  unsigned int r = (u + 0x7fffu + ((u >> 16) & 1u)) >> 16;
  return (u16)r;
}
static __device__ __forceinline__ float bf2f(u16 v) {
  return __uint_as_float(((u32)v) << 16);
}

static __device__ __forceinline__ u32 cvt_pk_bf16(float lo, float hi) {
  u32 r;
  asm volatile("v_cvt_pk_bf16_f32 %0, %1, %2" : "=v"(r) : "v"(lo), "v"(hi));
  return r;
}
// swaps a's upper-half lanes with b's lower-half lanes (gfx950).
static __device__ __forceinline__ void permswap(u32& a, u32& b) {
  asm volatile("v_permlane32_swap_b32 %0, %1" : "+v"(a), "+v"(b));
}

#define GLB(p) ((const __attribute__((address_space(1))) void*)(p))
#define LDS(p) ((__attribute__((address_space(3))) void*)(p))

// ---------------------------------------------------------------------------
// fp32 -> bf16 convert
// ---------------------------------------------------------------------------
__global__ void cvt_bf16_kernel(const float* __restrict__ in,
                                u16* __restrict__ out, int n) {
  int i = (blockIdx.x * 256 + threadIdx.x) * 8;
  if (i >= n) return;
  float4 a = *reinterpret_cast<const float4*>(in + i);
  float4 b = *reinterpret_cast<const float4*>(in + i + 4);
  short8 r;
  r[0] = (short)f2bf(a.x); r[1] = (short)f2bf(a.y);
  r[2] = (short)f2bf(a.z); r[3] = (short)f2bf(a.w);
  r[4] = (short)f2bf(b.x); r[5] = (short)f2bf(b.y);
  r[6] = (short)f2bf(b.z); r[7] = (short)f2bf(b.w);
  *reinterpret_cast<short8*>(out + i) = r;
}

// ---------------------------------------------------------------------------
// fused wq|wk|wv fp32 -> bf16 convert into contiguous wqkvb
// (n0, n1, n2 are multiples of 2048 -> no range straddles a thread)
// ---------------------------------------------------------------------------
__global__ void cvt3_bf16_kernel(const float* __restrict__ w0,
                                 const float* __restrict__ w1,
                                 const float* __restrict__ w2,
                                 u16* __restrict__ out,
                                 int n0, int n1, int n2) {
  int i = (blockIdx.x * 256 + threadIdx.x) * 8;
  const float* src;
  int off;
  if (i < n0) { src = w0; off = i; }
  else if (i < n0 + n1) { src = w1; off = i - n0; }
  else if (i < n0 + n1 + n2) { src = w2; off = i - n0 - n1; }
  else return;
  float4 a = *reinterpret_cast<const float4*>(src + off);
  float4 b = *reinterpret_cast<const float4*>(src + off + 4);
  short8 r;
  r[0] = (short)f2bf(a.x); r[1] = (short)f2bf(a.y);
  r[2] = (short)f2bf(a.z); r[3] = (short)f2bf(a.w);
  r[4] = (short)f2bf(b.x); r[5] = (short)f2bf(b.y);
  r[6] = (short)f2bf(b.z); r[7] = (short)f2bf(b.w);
  *reinterpret_cast<short8*>(out + i) = r;
}

// ---------------------------------------------------------------------------
// bias concat (replaces 3 hipMemcpyAsync)
// ---------------------------------------------------------------------------
__global__ void bias_concat_kernel(const float* __restrict__ bq,
                                   const float* __restrict__ bk,
                                   const float* __restrict__ bv,
                                   float* __restrict__ dst) {
  int i = blockIdx.x * 256 + threadIdx.x;
  if (i >= NQKV_) return;
  float v;
  if (i < HQ * DH) v = bq[i];
  else if (i < HQ * DH + HKV * DH) v = bk[i - HQ * DH];
  else v = bv[i - HQ * DH - HKV * DH];
  dst[i] = v;
}

// ---------------------------------------------------------------------------
// RoPE table
// ---------------------------------------------------------------------------
__global__ void rope_tab_kernel(float* __restrict__ ctab, float* __restrict__ stab) {
  int idx = blockIdx.x * 256 + threadIdx.x;
  if (idx >= L_ * (DH / 2)) return;
  int pos = idx >> 6;
  int f = idx & 63;
  float inv_freq = powf(10000.0f, -(float)f * (1.0f / 64.0f));
  float ang = (float)pos * inv_freq;
  float s, c;
  sincosf(ang, &s, &c);
  ctab[idx] = c;
  stab[idx] = s;
}

// ---------------------------------------------------------------------------
// RoPE apply from bf16 fused-qkv buffer -> bf16 head-major buffer (K only)
// ---------------------------------------------------------------------------
__global__ void rope_convert_kernel(const u16* __restrict__ in,
                                    u16* __restrict__ outb,
                                    const float* __restrict__ ctab,
                                    const float* __restrict__ stab,
                                    int H, int rowStride, int colOff,
                                    float scale, int total) {
  int idx = blockIdx.x * 256 + threadIdx.x;
  if (idx >= total) return;
  int f = idx & 63;
  int row = idx >> 6;
  int h = row % H;
  int bl = row / H;
  int l = bl & (L_ - 1);
  size_t sbase = (size_t)bl * rowStride + colOff + (size_t)h * DH;
  size_t dbase = (size_t)bl * ((size_t)H * DH) + (size_t)h * DH;
  float x1 = bf2f(in[sbase + f]);
  float x2 = bf2f(in[sbase + 64 + f]);
  float c = ctab[l * 64 + f];
  float s = stab[l * 64 + f];
  outb[dbase + f]      = f2bf((x1 * c - x2 * s) * scale);
  outb[dbase + 64 + f] = f2bf((x2 * c + x1 * s) * scale);
}

// ---------------------------------------------------------------------------
// V transpose from bf16 qkv buffer: -> Vt[(b*HKV+kvh)*128+d][key]
// ---------------------------------------------------------------------------
__global__ __launch_bounds__(256) void transpose_v_kernel(
    const u16* __restrict__ v, u16* __restrict__ Vt,
    int rowStride, int colOff) {
  __shared__ u16 tile[64][68];
  const int k0 = blockIdx.x * 64;
  const int d0 = blockIdx.y * 64;
  const int bk = blockIdx.z;
  const int b = bk / HKV, kvh = bk % HKV;
#pragma unroll
  for (int i = 0; i < 4; ++i) {
    int key = i * 16 + (threadIdx.x >> 4);
    int d4 = (threadIdx.x & 15) * 4;
    *reinterpret_cast<ushort2*>(&tile[key][d4]) = *reinterpret_cast<const ushort2*>(
        &v[(size_t)(b * L_ + k0 + key) * rowStride + colOff + kvh * DH + d0 + d4]);
    *reinterpret_cast<ushort2*>(&tile[key][d4 + 2]) = *reinterpret_cast<const ushort2*>(
        &v[(size_t)(b * L_ + k0 + key) * rowStride + colOff + kvh * DH + d0 + d4 + 2]);
  }
  __syncthreads();
  const int d = threadIdx.x >> 2;
  const int kq = (threadIdx.x & 3) * 16;
  u16* orow = Vt + ((size_t)(bk * DH + d0 + d)) * L_ + k0 + kq;
#pragma unroll
  for (int j = 0; j < 16; ++j) orow[j] = tile[kq + j][d];
}

// ---------------------------------------------------------------------------
// bf16 MFMA GEMM: 128x128 tile, BK=64, single-buffer, 2x __syncthreads,
// XOR-slot LDS mapping (R14/R15-proven). 32 MFMAs per K-step.
// ---------------------------------------------------------------------------
#define GBM 128
#define GBN 128
#define GBK 64

template <bool BF16OUT>
__global__ __launch_bounds__(256) void gemm_bf16_kernel(
    const u16* __restrict__ A, const u16* __restrict__ W,
    const float* __restrict__ bias, void* __restrict__ Cv,
    int M, int N, int K)
{
  __shared__ u16 As[GBM * GBK];   // 16 KB
  __shared__ u16 Bs[GBN * GBK];   // 16 KB

  const int tid = threadIdx.x;
  const int wave = tid >> 6;
  const int lane = tid & 63;
  const int lr = lane & 15;
  const int lg = lane >> 4;
  const int bm = blockIdx.y * GBM;
  const int bn = blockIdx.x * GBN;
  const int wm = (wave >> 1) * 64;
  const int wn = (wave & 1) * 64;

  f32x4 acc[4][4];
#pragma unroll
  for (int i = 0; i < 4; ++i)
#pragma unroll
    for (int j = 0; j < 4; ++j) acc[i][j] = (f32x4){0.f, 0.f, 0.f, 0.f};

  const u16* gA[4];
  const u16* gB[4];
  u16* lA[4];
  u16* lB[4];
#pragma unroll
  for (int t = 0; t < 4; ++t) {
    int c = t * 256 + wave * 64 + lane;
    int row = c >> 3;
    int slog = (c & 7) ^ (row & 7);
    gA[t] = A + (size_t)(bm + row) * K + slog * 8;
    gB[t] = W + (size_t)(bn + row) * K + slog * 8;
    lA[t] = &As[(t * 256 + wave * 64) * 8];
    lB[t] = &Bs[(t * 256 + wave * 64) * 8];
  }

  const int fx = lr & 7;

  for (int k0 = 0; k0 < K; k0 += GBK) {
    __syncthreads();
#pragma unroll
    for (int t = 0; t < 4; ++t) {
      __builtin_amdgcn_global_load_lds(GLB(gA[t] + k0), LDS(lA[t]), 16, 0, 0);
      __builtin_amdgcn_global_load_lds(GLB(gB[t] + k0), LDS(lB[t]), 16, 0, 0);
    }
    __syncthreads();

#pragma unroll
    for (int kk = 0; kk < 2; ++kk) {
      short8 af[4], bf[4];
#pragma unroll
      for (int mi = 0; mi < 4; ++mi) {
        int row = wm + mi * 16 + lr;
        int slot = (kk * 4 + lg) ^ fx;
        af[mi] = *reinterpret_cast<const short8*>(&As[row * 64 + slot * 8]);
      }
#pragma unroll
      for (int ni = 0; ni < 4; ++ni) {
        int row = wn + ni * 16 + lr;
        int slot = (kk * 4 + lg) ^ fx;
        bf[ni] = *reinterpret_cast<const short8*>(&Bs[row * 64 + slot * 8]);
      }
#pragma unroll
      for (int mi = 0; mi < 4; ++mi)
#pragma unroll
        for (int ni = 0; ni < 4; ++ni)
          acc[mi][ni] = __builtin_amdgcn_mfma_f32_16x16x32_bf16(af[mi], bf[ni], acc[mi][ni], 0, 0, 0);
    }
  }

#pragma unroll
  for (int ni = 0; ni < 4; ++ni) {
    int col = bn + wn + ni * 16 + lr;
    float bv = (bias != nullptr) ? bias[col] : 0.f;
#pragma unroll
    for (int mi = 0; mi < 4; ++mi) {
#pragma unroll
      for (int r = 0; r < 4; ++r) {
        int row = bm + wm + mi * 16 + lg * 4 + r;
        float val = acc[mi][ni][r] + bv;
        if constexpr (BF16OUT)
          ((u16*)Cv)[(size_t)row * N + col] = f2bf(val);
        else
          ((float*)Cv)[(size_t)row * N + col] = val;
      }
    }
  }
}

// ---------------------------------------------------------------------------
// Flash attention (R16/R19-proven structure) + fused in-register Q RoPE.
// KVBLK=64, 4-wave blocks (4 heads), K+V LDS double-buffered, counted-vmcnt
// pipeline. Grid 512 = 2 blocks/CU (blocks i, i+256 carry tiles 63-u and u).
// Q read directly from qkvb (stride NQKV_); rope pair (f, f+64) is
// (qB[ss], qB[ss+4]) -> thread-local rotation, one-time prologue.
// Output goes to a non-aliasing buffer `ao`.
// ---------------------------------------------------------------------------
__device__ __forceinline__ void pack16(const float p[16], short8& pa0, short8& pa1) {
  u32 w[8];
#pragma unroll
  for (int t = 0; t < 8; ++t) w[t] = cvt_pk_bf16(p[2 * t], p[2 * t + 1]);
  permswap(w[0], w[2]); permswap(w[1], w[3]);
  permswap(w[4], w[6]); permswap(w[5], w[7]);
  pa0 = __builtin_bit_cast(short8, (u32x4){w[0], w[1], w[2], w[3]});
  pa1 = __builtin_bit_cast(short8, (u32x4){w[4], w[5], w[6], w[7]});
}

__device__ __forceinline__ void head_epilogue(
    const f32x16 O[4], float lrun, int l5, int hi, float* cbufw,
    u16* __restrict__ obase)
{
  float ltot = lrun + __shfl_xor(lrun, 32);
  if (hi == 0) cbufw[l5] = ltot;
  float4 lv[4];
#pragma unroll
  for (int gg = 0; gg < 4; ++gg)
    lv[gg] = *reinterpret_cast<const float4*>(&cbufw[8 * gg + 4 * hi]);
#pragma unroll
  for (int r = 0; r < 16; ++r) {
    int crow = (r & 3) + 8 * (r >> 2) + 4 * hi;
    float inv = __builtin_amdgcn_rcpf((&lv[r >> 2].x)[r & 3]);
    u16* orow = obase + (size_t)crow * (HQ * DH) + l5;
#pragma unroll
    for (int n = 0; n < 4; ++n)
      orow[n * 32] = f2bf(O[n][r] * inv);
  }
}

__global__ __launch_bounds__(256, 2) void flash_attn_pipe_kernel(
    const u16* __restrict__ Qsrc, const u16* __restrict__ Kb,
    const u16* __restrict__ Vt, u16* __restrict__ ao,
    const float* __restrict__ ctab, const float* __restrict__ stab)
{
  const int tid = threadIdx.x;
  const int wave = tid >> 6;
  const int lane = tid & 63;
  const int l5 = lane & 31;
  const int hi = lane >> 5;

  const int bid = blockIdx.x;
  const int half = bid >> 8;
  const int u = (bid >> 3) & 31;
  const int x = bid & 7;
  const int c = x >> 1;
  const int hh = x & 1;
  const int b = c >> 1, kvh = c & 1;
  const int h = kvh * 8 + hh * 4 + wave;
  const int t = half ? u : (63 - u);
  const int q0 = 32 * t;
  const int nst = (t + 2) >> 1;          // 64-key steps
  const int bk = b * HKV + kvh;

  __shared__ u16 Ks[2][64 * 128];   // 32 KB; 16 slots/row, phys = slot^(key&15)
  __shared__ u16 Vs[2][128 * 64];   // 32 KB; 8 slots/row,  phys = slot^(d&7)
  __shared__ __align__(16) float cbuf[4][32];
  float* cbufw = cbuf[wave];

  const u16* Kg = Kb + (size_t)(b * L_) * (HKV * DH) + kvh * DH;
  const u16* Vg = Vt + (size_t)(bk * DH) * L_;

  // 8 global_load_lds per thread per stage (4 K + 4 V chunks)
  auto stage = [&](int s) {
    const int buf = s & 1;
    const int j0 = s * 64;
#pragma unroll
    for (int q = 0; q < 4; ++q) {
      int cnk = q * 256 + tid;            // K chunk 0..1023
      int key = cnk >> 4, phys = cnk & 15;
      int slog = phys ^ (key & 15);
      const u16* src = Kg + (size_t)(j0 + key) * (HKV * DH) + slog * 8;
      __builtin_amdgcn_global_load_lds(GLB(src), LDS(&Ks[buf][(q * 256 + wave * 64) * 8]), 16, 0, 0);
    }
#pragma unroll
    for (int q = 0; q < 4; ++q) {
      int cnk = q * 256 + tid;            // V chunk 0..1023
      int d = cnk >> 3, phys = cnk & 7;
      int slog = phys ^ (d & 7);
      const u16* src = Vg + (size_t)d * L_ + j0 + slog * 8;
      __builtin_amdgcn_global_load_lds(GLB(src), LDS(&Vs[buf][(q * 256 + wave * 64) * 8]), 16, 0, 0);
    }
  };

  // ---- Q load from qkvb + in-register RoPE + scale (one-time) ----
  const u16* qrow = Qsrc + ((size_t)(b * L_ + q0 + l5)) * NQKV_ + h * DH + hi * 8;
  short8 qB[8];
#pragma unroll
  for (int ss = 0; ss < 8; ++ss)
    qB[ss] = *reinterpret_cast<const short8*>(qrow + ss * 16);
  {
    const float qscale = 0.08838834764831845f;  // 1/sqrt(128)
    const float* cb = ctab + (size_t)(q0 + l5) * 64 + hi * 8;
    const float* sb = stab + (size_t)(q0 + l5) * 64 + hi * 8;
#pragma unroll
    for (int ss = 0; ss < 4; ++ss) {
      float4 c0 = *reinterpret_cast<const float4*>(cb + ss * 16);
      float4 c1 = *reinterpret_cast<const float4*>(cb + ss * 16 + 4);
      float4 s0 = *reinterpret_cast<const float4*>(sb + ss * 16);
      float4 s1 = *reinterpret_cast<const float4*>(sb + ss * 16 + 4);
      float cj[8] = {c0.x, c0.y, c0.z, c0.w, c1.x, c1.y, c1.z, c1.w};
      float sj[8] = {s0.x, s0.y, s0.z, s0.w, s1.x, s1.y, s1.z, s1.w};
#pragma unroll
      for (int j = 0; j < 8; ++j) {
        float x1 = bf2f((u16)qB[ss][j]);
        float x2 = bf2f((u16)qB[ss + 4][j]);
        qB[ss][j]     = (short)f2bf((x1 * cj[j] - x2 * sj[j]) * qscale);
        qB[ss + 4][j] = (short)f2bf((x2 * cj[j] + x1 * sj[j]) * qscale);
      }
    }
  }

  f32x16 O[4];
#pragma unroll
  for (int n = 0; n < 4; ++n)
#pragma unroll
    for (int r = 0; r < 16; ++r) O[n][r] = 0.f;
  float mrun = -INFINITY, lrun = 0.f;

  stage(0);
  if (nst > 1) stage(1);

#pragma unroll 1
  for (int s = 0; s < nst; ++s) {
    if (s + 1 < nst) { asm volatile("s_waitcnt vmcnt(8)" ::: "memory"); }
    else             { asm volatile("s_waitcnt vmcnt(0)" ::: "memory"); }
    __builtin_amdgcn_s_barrier();          // buf[s&1] landed for all waves
    __builtin_amdgcn_sched_barrier(0);

    const int cur = s & 1;
    const int j0 = s * 64;
    const int kx = l5 & 15;

    // subtile A: keys j0 + 0..31
    short8 kcA[8], vvA[8];
#pragma unroll
    for (int ss = 0; ss < 8; ++ss) {
      int phys = (2 * ss + hi) ^ kx;
      kcA[ss] = *reinterpret_cast<const short8*>(&Ks[cur][l5 * 128 + phys * 8]);
    }
#pragma unroll
    for (int n = 0; n < 4; ++n) {
#pragma unroll
      for (int cc = 0; cc < 2; ++cc) {
        int d = n * 32 + l5;
        int phys = (cc * 2 + hi) ^ (d & 7);
        vvA[n * 2 + cc] = *reinterpret_cast<const short8*>(&Vs[cur][d * 64 + phys * 8]);
      }
    }
    f32x16 Sa;
#pragma unroll
    for (int r = 0; r < 16; ++r) Sa[r] = 0.f;
#pragma unroll
    for (int ss = 0; ss < 8; ++ss)
      Sa = __builtin_amdgcn_mfma_f32_32x32x16_bf16(kcA[ss], qB[ss], Sa, 0, 0, 0);

    // subtile B: keys j0 + 32..63
    short8 kcB[8], vvB[8];
#pragma unroll
    for (int ss = 0; ss < 8; ++ss) {
      int phys = (2 * ss + hi) ^ kx;
      kcB[ss] = *reinterpret_cast<const short8*>(&Ks[cur][(32 + l5) * 128 + phys * 8]);
    }
#pragma unroll
    for (int n = 0; n < 4; ++n) {
#pragma unroll
      for (int cc = 0; cc < 2; ++cc) {
        int d = n * 32 + l5;
        int phys = (4 + cc * 2 + hi) ^ (d & 7);
        vvB[n * 2 + cc] = *reinterpret_cast<const short8*>(&Vs[cur][d * 64 + phys * 8]);
      }
    }
    f32x16 Sb;
#pragma unroll
    for (int r = 0; r < 16; ++r) Sb[r] = 0.f;
#pragma unroll
    for (int ss = 0; ss < 8; ++ss)
      Sb = __builtin_amdgcn_mfma_f32_32x32x16_bf16(kcB[ss], qB[ss], Sb, 0, 0, 0);

    asm volatile("s_waitcnt lgkmcnt(0)" ::: "memory");
    __builtin_amdgcn_sched_barrier(0);
    __builtin_amdgcn_s_barrier();          // all waves done reading buf[cur]
    if (s + 2 < nst) stage(s + 2);         // overwrite buf[cur] for step s+2

    float sa[16], sb[16];
#pragma unroll
    for (int r = 0; r < 16; ++r) { sa[r] = Sa[r]; sb[r] = Sb[r]; }

    // causal masks
    if (j0 == q0) {
#pragma unroll
      for (int r = 0; r < 16; ++r) {
        int crow = (r & 3) + 8 * (r >> 2) + 4 * hi;
        if (crow > l5) sa[r] = -INFINITY;
        sb[r] = -INFINITY;                 // keys q0+32.. all beyond queries
      }
    } else if (j0 + 32 == q0) {
#pragma unroll
      for (int r = 0; r < 16; ++r) {
        int crow = (r & 3) + 8 * (r >> 2) + 4 * hi;
        if (crow > l5) sb[r] = -INFINITY;
      }
    }

    // row max over 64 keys: in-register trees + one cross-half exchange
    float t8[8], t4[4];
#pragma unroll
    for (int r = 0; r < 8; ++r) t8[r] = fmaxf(fmaxf(sa[2 * r], sa[2 * r + 1]),
                                              fmaxf(sb[2 * r], sb[2 * r + 1]));
#pragma unroll
    for (int r = 0; r < 4; ++r) t4[r] = fmaxf(t8[2 * r], t8[2 * r + 1]);
    float pmax = fmaxf(fmaxf(t4[0], t4[1]), fmaxf(t4[2], t4[3]));
    pmax = fmaxf(pmax, __shfl_xor(pmax, 32));

    // defer-max rescale (T13)
    if (__any(pmax > mrun + 8.0f)) {
      float mnew = fmaxf(mrun, pmax);
      float corr = __expf(mrun - mnew);
      mrun = mnew;
      lrun *= corr;
      if (hi == 0) cbufw[l5] = corr;
      float4 cr[4];
#pragma unroll
      for (int g = 0; g < 4; ++g)
        cr[g] = *reinterpret_cast<const float4*>(&cbufw[8 * g + 4 * hi]);
#pragma unroll
      for (int n = 0; n < 4; ++n)
#pragma unroll
        for (int r = 0; r < 16; ++r)
          O[n][r] *= (&cr[r >> 2].x)[r & 3];
    }

    // P = exp(S - m); per-half partial sum (cross-half merge at epilogue)
    float pa_[16], pb_[16];
#pragma unroll
    for (int r = 0; r < 16; ++r) {
      pa_[r] = __expf(sa[r] - mrun);
      pb_[r] = __expf(sb[r] - mrun);
    }
#pragma unroll
    for (int r = 0; r < 8; ++r) t8[r] = (pa_[2 * r] + pa_[2 * r + 1]) +
                                        (pb_[2 * r] + pb_[2 * r + 1]);
#pragma unroll
    for (int r = 0; r < 4; ++r) t4[r] = t8[2 * r] + t8[2 * r + 1];
    lrun += (t4[0] + t4[1]) + (t4[2] + t4[3]);

    // pack P -> A-fragments (T12, R5-validated per 16-value group)
    short8 paA0, paA1, paB0, paB1;
    pack16(pa_, paA0, paA1);
    pack16(pb_, paB0, paB1);

    // O += P V (4 k-slots of 16)
#pragma unroll
    for (int n = 0; n < 4; ++n) {
      O[n] = __builtin_amdgcn_mfma_f32_32x32x16_bf16(paA0, vvA[n * 2 + 0], O[n], 0, 0, 0);
      O[n] = __builtin_amdgcn_mfma_f32_32x32x16_bf16(paA1, vvA[n * 2 + 1], O[n], 0, 0, 0);
      O[n] = __builtin_amdgcn_mfma_f32_32x32x16_bf16(paB0, vvB[n * 2 + 0], O[n], 0, 0, 0);
      O[n] = __builtin_amdgcn_mfma_f32_32x32x16_bf16(paB1, vvB[n * 2 + 1], O[n], 0, 0, 0);
    }
  }

  u16* obase = ao + (size_t)(b * L_ + q0) * (HQ * DH) + h * DH;
  head_epilogue(O, lrun, l5, hi, cbufw, obase);
}

// ---------------------------------------------------------------------------
// launch
// ---------------------------------------------------------------------------
extern "C" void kernel_launch(void* const* d_in, const int* in_sizes, int n_in,
                              void* d_out, int out_size, void* d_ws, size_t ws_size,
                              hipStream_t stream) {
  const float* x  = (const float*)d_in[0];
  const float* wq = (const float*)d_in[1];
  const float* wk = (const float*)d_in[2];
  const float* wv = (const float*)d_in[3];
  const float* wo = (const float*)d_in[4];
  const float* bq = (const float*)d_in[5];
  const float* bk = (const float*)d_in[6];
  const float* bv = (const float*)d_in[7];
  float* out = (float*)d_out;

  const int M = B_ * L_;
  const int NQKV = NQKV_;                       // 2560
  const size_t QN = (size_t)B_ * L_ * HQ * DH;  // 8388608
  const size_t KN = (size_t)B_ * L_ * HKV * DH; // 1048576
  const size_t TN = (size_t)L_ * (DH / 2);      // 131072

  float* ws = (float*)d_ws;
  float* ct   = ws;
  float* st   = ct + TN;
  float* bqkv = st + TN;
  u16* qkvb   = (u16*)(bqkv + NQKV);        // bf16 QKV projection output
  u16* xb     = qkvb + (size_t)M * NQKV;    // x bf16; reused for wo bf16 later
  u16* wqkvb  = xb + (size_t)M * E_;
  u16* ao     = wqkvb + (size_t)NQKV * E_;  // attention output (bf16)
  u16* Kbf    = ao + QN;
  u16* Vt     = Kbf + KN;
  u16* wob    = xb;                          // alias: xb dead after QKV GEMM

  rope_tab_kernel<<<(L_ * (DH / 2) + 255) / 256, 256, 0, stream>>>(ct, st);

  cvt_bf16_kernel<<<(int)(QN / 8 / 256), 256, 0, stream>>>(x, xb, (int)QN);
  cvt3_bf16_kernel<<<(NQKV * E_) / 8 / 256, 256, 0, stream>>>(
      wq, wk, wv, wqkvb, HQ * DH * E_, HKV * DH * E_, HKV * DH * E_);
  bias_concat_kernel<<<(NQKV + 255) / 256, 256, 0, stream>>>(bq, bk, bv, bqkv);

  // fused QKV projection: [4096][2560] bf16
  gemm_bf16_kernel<true><<<dim3(NQKV / GBN, M / GBM), 256, 0, stream>>>(
      xb, wqkvb, bqkv, qkvb, M, NQKV, E_);

  // K rope (writes Kbf); V transpose (writes Vt); Q rope fused into attention
  {
    int totk = B_ * L_ * HKV * 64;
    rope_convert_kernel<<<(totk + 255) / 256, 256, 0, stream>>>(
        qkvb, Kbf, ct, st, HKV, NQKV, HQ * DH, 1.0f, totk);
  }
  transpose_v_kernel<<<dim3(L_ / 64, DH / 64, B_ * HKV), 256, 0, stream>>>(
      qkvb, Vt, NQKV, HQ * DH + HKV * DH);

  flash_attn_pipe_kernel<<<dim3(512), 256, 0, stream>>>(
      qkvb, Kbf, Vt, ao, ct, st);

  cvt_bf16_kernel<<<(E_ * E_) / 8 / 256, 256, 0, stream>>>(wo, wob, E_ * E_);
  gemm_bf16_kernel<false><<<dim3(E_ / GBN, M / GBM), 256, 0, stream>>>(
      ao, wob, nullptr, out, M, E_, E_);
}

// Round 21
// 187.994 us; speedup vs baseline: 1.3786x; 1.0276x over previous
//
#include <hip/hip_runtime.h>
#include <math.h>

#define B_ 2
#define L_ 2048
#define E_ 2048
#define HQ 16
#define HKV 2
#define DH 128
#define NQKV_ 2560

typedef unsigned short u16;
typedef unsigned int u32;
typedef __attribute__((ext_vector_type(8))) short short8;
typedef __attribute__((ext_vector_type(4))) float f32x4;
typedef __attribute__((ext_vector_type(16))) float f32x16;
typedef __attribute__((ext_vector_type(4))) u32 u32x4;

static __device__ __forceinline__ u16 f2bf(float f) {
  unsigned int u = __float_as_uint(f);
  unsigned int r = (u + 0x7fffu + ((u >> 16) & 1u)) >> 16;
  return (u16)r;
}
static __device__ __forceinline__ float bf2f(u16 v) {
  return __uint_as_float(((u32)v) << 16);
}

static __device__ __forceinline__ u32 cvt_pk_bf16(float lo, float hi) {
  u32 r;
  asm volatile("v_cvt_pk_bf16_f32 %0, %1, %2" : "=v"(r) : "v"(lo), "v"(hi));
  return r;
}
// swaps a's upper-half lanes with b's lower-half lanes (gfx950).
static __device__ __forceinline__ void permswap(u32& a, u32& b) {
  asm volatile("v_permlane32_swap_b32 %0, %1" : "+v"(a), "+v"(b));
}

#define GLB(p) ((const __attribute__((address_space(1))) void*)(p))
#define LDS(p) ((__attribute__((address_space(3))) void*)(p))

// ---------------------------------------------------------------------------
// fp32 -> bf16 convert
// ---------------------------------------------------------------------------
__global__ void cvt_bf16_kernel(const float* __restrict__ in,
                                u16* __restrict__ out, int n) {
  int i = (blockIdx.x * 256 + threadIdx.x) * 8;
  if (i >= n) return;
  float4 a = *reinterpret_cast<const float4*>(in + i);
  float4 b = *reinterpret_cast<const float4*>(in + i + 4);
  short8 r;
  r[0] = (short)f2bf(a.x); r[1] = (short)f2bf(a.y);
  r[2] = (short)f2bf(a.z); r[3] = (short)f2bf(a.w);
  r[4] = (short)f2bf(b.x); r[5] = (short)f2bf(b.y);
  r[6] = (short)f2bf(b.z); r[7] = (short)f2bf(b.w);
  *reinterpret_cast<short8*>(out + i) = r;
}

// ---------------------------------------------------------------------------
// fused wq|wk|wv -> wqkvb  and  wo -> wob, one launch.
// All range sizes are multiples of 2048 -> no 8-elem group straddles.
// ---------------------------------------------------------------------------
__global__ void cvt4_bf16_kernel(const float* __restrict__ w0,
                                 const float* __restrict__ w1,
                                 const float* __restrict__ w2,
                                 const float* __restrict__ w3,
                                 u16* __restrict__ out012,
                                 u16* __restrict__ out3,
                                 int n0, int n1, int n2, int n3) {
  int i = (blockIdx.x * 256 + threadIdx.x) * 8;
  const float* src;
  u16* dst;
  int off;
  if (i < n0) { src = w0; dst = out012; off = i; }
  else if (i < n0 + n1) { src = w1; dst = out012; off = i - n0; i = i; }
  else if (i < n0 + n1 + n2) { src = w2; dst = out012; off = i - n0 - n1; }
  else if (i < n0 + n1 + n2 + n3) { src = w3; dst = out3; off = i - n0 - n1 - n2; }
  else return;
  int dsti = (dst == out3) ? off : i;
  float4 a = *reinterpret_cast<const float4*>(src + off);
  float4 b = *reinterpret_cast<const float4*>(src + off + 4);
  short8 r;
  r[0] = (short)f2bf(a.x); r[1] = (short)f2bf(a.y);
  r[2] = (short)f2bf(a.z); r[3] = (short)f2bf(a.w);
  r[4] = (short)f2bf(b.x); r[5] = (short)f2bf(b.y);
  r[6] = (short)f2bf(b.z); r[7] = (short)f2bf(b.w);
  *reinterpret_cast<short8*>(dst + dsti) = r;
}

// ---------------------------------------------------------------------------
// bias concat
// ---------------------------------------------------------------------------
__global__ void bias_concat_kernel(const float* __restrict__ bq,
                                   const float* __restrict__ bk,
                                   const float* __restrict__ bv,
                                   float* __restrict__ dst) {
  int i = blockIdx.x * 256 + threadIdx.x;
  if (i >= NQKV_) return;
  float v;
  if (i < HQ * DH) v = bq[i];
  else if (i < HQ * DH + HKV * DH) v = bk[i - HQ * DH];
  else v = bv[i - HQ * DH - HKV * DH];
  dst[i] = v;
}

// ---------------------------------------------------------------------------
// RoPE table
// ---------------------------------------------------------------------------
__global__ void rope_tab_kernel(float* __restrict__ ctab, float* __restrict__ stab) {
  int idx = blockIdx.x * 256 + threadIdx.x;
  if (idx >= L_ * (DH / 2)) return;
  int pos = idx >> 6;
  int f = idx & 63;
  float inv_freq = powf(10000.0f, -(float)f * (1.0f / 64.0f));
  float ang = (float)pos * inv_freq;
  float s, c;
  sincosf(ang, &s, &c);
  ctab[idx] = c;
  stab[idx] = s;
}

// ---------------------------------------------------------------------------
// fused K-rope + V-transpose from bf16 qkv buffer (block-granular split).
// blocks [0, KROPE_BLKS): K rope -> Kbf head-major
// blocks [KROPE_BLKS, +256): V transpose -> Vt[(b*HKV+kvh)*128+d][key]
// ---------------------------------------------------------------------------
#define KROPE_BLKS (B_ * L_ * HKV * 64 / 256)   // 2048

__global__ __launch_bounds__(256) void kv_prep_kernel(
    const u16* __restrict__ qkv, u16* __restrict__ Kbf, u16* __restrict__ Vt,
    const float* __restrict__ ctab, const float* __restrict__ stab) {
  __shared__ u16 tile[64][68];
  if (blockIdx.x < KROPE_BLKS) {
    int idx = blockIdx.x * 256 + threadIdx.x;
    int f = idx & 63;
    int row = idx >> 6;          // (b*L+l)*HKV + h
    int h = row % HKV;
    int bl = row / HKV;
    int l = bl & (L_ - 1);
    size_t sbase = (size_t)bl * NQKV_ + HQ * DH + (size_t)h * DH;
    size_t dbase = (size_t)bl * ((size_t)HKV * DH) + (size_t)h * DH;
    float x1 = bf2f(qkv[sbase + f]);
    float x2 = bf2f(qkv[sbase + 64 + f]);
    float c = ctab[l * 64 + f];
    float s = stab[l * 64 + f];
    Kbf[dbase + f]      = f2bf(x1 * c - x2 * s);
    Kbf[dbase + 64 + f] = f2bf(x2 * c + x1 * s);
    return;
  }
  // V transpose
  const int vb = blockIdx.x - KROPE_BLKS;   // 0..255
  const int k0 = (vb & 31) * 64;
  const int d0 = ((vb >> 5) & 1) * 64;
  const int bk = vb >> 6;                   // b*HKV + kvh
  const int b = bk / HKV, kvh = bk % HKV;
  const int colOff = HQ * DH + HKV * DH;
#pragma unroll
  for (int i = 0; i < 4; ++i) {
    int key = i * 16 + (threadIdx.x >> 4);
    int d4 = (threadIdx.x & 15) * 4;
    *reinterpret_cast<ushort2*>(&tile[key][d4]) = *reinterpret_cast<const ushort2*>(
        &qkv[(size_t)(b * L_ + k0 + key) * NQKV_ + colOff + kvh * DH + d0 + d4]);
    *reinterpret_cast<ushort2*>(&tile[key][d4 + 2]) = *reinterpret_cast<const ushort2*>(
        &qkv[(size_t)(b * L_ + k0 + key) * NQKV_ + colOff + kvh * DH + d0 + d4 + 2]);
  }
  __syncthreads();
  const int d = threadIdx.x >> 2;
  const int kq = (threadIdx.x & 3) * 16;
  u16* orow = Vt + ((size_t)(bk * DH + d0 + d)) * L_ + k0 + kq;
#pragma unroll
  for (int j = 0; j < 16; ++j) orow[j] = tile[kq + j][d];
}

// ---------------------------------------------------------------------------
// bf16 MFMA GEMM: 128x128 tile, BK=64, single-buffer, 2x __syncthreads,
// XOR-slot LDS mapping (R14/R15-proven) + bijective XCD-chunked swizzle
// (1D grid, nwg % 8 == 0). 32 MFMAs per K-step.
// ---------------------------------------------------------------------------
#define GBM 128
#define GBN 128
#define GBK 64

template <bool BF16OUT>
__global__ __launch_bounds__(256) void gemm_bf16_kernel(
    const u16* __restrict__ A, const u16* __restrict__ W,
    const float* __restrict__ bias, void* __restrict__ Cv,
    int M, int N, int K)
{
  __shared__ u16 As[GBM * GBK];   // 16 KB
  __shared__ u16 Bs[GBN * GBK];   // 16 KB

  const int tid = threadIdx.x;
  const int wave = tid >> 6;
  const int lane = tid & 63;
  const int lr = lane & 15;
  const int lg = lane >> 4;

  // bijective XCD-chunked swizzle (R13-validated mapping; nwg % 8 == 0)
  const int nwg = gridDim.x;
  const int qch = nwg >> 3;
  const int bid = blockIdx.x;
  const int wgid = (bid & 7) * qch + (bid >> 3);
  const int nx = N / GBN;
  const int bm = (wgid / nx) * GBM;
  const int bn = (wgid % nx) * GBN;

  const int wm = (wave >> 1) * 64;
  const int wn = (wave & 1) * 64;

  f32x4 acc[4][4];
#pragma unroll
  for (int i = 0; i < 4; ++i)
#pragma unroll
    for (int j = 0; j < 4; ++j) acc[i][j] = (f32x4){0.f, 0.f, 0.f, 0.f};

  const u16* gA[4];
  const u16* gB[4];
  u16* lA[4];
  u16* lB[4];
#pragma unroll
  for (int t = 0; t < 4; ++t) {
    int c = t * 256 + wave * 64 + lane;
    int row = c >> 3;
    int slog = (c & 7) ^ (row & 7);
    gA[t] = A + (size_t)(bm + row) * K + slog * 8;
    gB[t] = W + (size_t)(bn + row) * K + slog * 8;
    lA[t] = &As[(t * 256 + wave * 64) * 8];
    lB[t] = &Bs[(t * 256 + wave * 64) * 8];
  }

  const int fx = lr & 7;

  for (int k0 = 0; k0 < K; k0 += GBK) {
    __syncthreads();
#pragma unroll
    for (int t = 0; t < 4; ++t) {
      __builtin_amdgcn_global_load_lds(GLB(gA[t] + k0), LDS(lA[t]), 16, 0, 0);
      __builtin_amdgcn_global_load_lds(GLB(gB[t] + k0), LDS(lB[t]), 16, 0, 0);
    }
    __syncthreads();

#pragma unroll
    for (int kk = 0; kk < 2; ++kk) {
      short8 af[4], bf[4];
#pragma unroll
      for (int mi = 0; mi < 4; ++mi) {
        int row = wm + mi * 16 + lr;
        int slot = (kk * 4 + lg) ^ fx;
        af[mi] = *reinterpret_cast<const short8*>(&As[row * 64 + slot * 8]);
      }
#pragma unroll
      for (int ni = 0; ni < 4; ++ni) {
        int row = wn + ni * 16 + lr;
        int slot = (kk * 4 + lg) ^ fx;
        bf[ni] = *reinterpret_cast<const short8*>(&Bs[row * 64 + slot * 8]);
      }
#pragma unroll
      for (int mi = 0; mi < 4; ++mi)
#pragma unroll
        for (int ni = 0; ni < 4; ++ni)
          acc[mi][ni] = __builtin_amdgcn_mfma_f32_16x16x32_bf16(af[mi], bf[ni], acc[mi][ni], 0, 0, 0);
    }
  }

#pragma unroll
  for (int ni = 0; ni < 4; ++ni) {
    int col = bn + wn + ni * 16 + lr;
    float bv = (bias != nullptr) ? bias[col] : 0.f;
#pragma unroll
    for (int mi = 0; mi < 4; ++mi) {
#pragma unroll
      for (int r = 0; r < 4; ++r) {
        int row = bm + wm + mi * 16 + lg * 4 + r;
        float val = acc[mi][ni][r] + bv;
        if constexpr (BF16OUT)
          ((u16*)Cv)[(size_t)row * N + col] = f2bf(val);
        else
          ((float*)Cv)[(size_t)row * N + col] = val;
      }
    }
  }
}

// ---------------------------------------------------------------------------
// Flash attention (R16/R19-proven structure) + fused in-register Q RoPE.
// KVBLK=64, 4-wave blocks (4 heads), K+V LDS double-buffered, counted-vmcnt
// pipeline. Grid 512 = 2 blocks/CU (blocks i, i+256 carry tiles 63-u and u).
// ---------------------------------------------------------------------------
__device__ __forceinline__ void pack16(const float p[16], short8& pa0, short8& pa1) {
  u32 w[8];
#pragma unroll
  for (int t = 0; t < 8; ++t) w[t] = cvt_pk_bf16(p[2 * t], p[2 * t + 1]);
  permswap(w[0], w[2]); permswap(w[1], w[3]);
  permswap(w[4], w[6]); permswap(w[5], w[7]);
  pa0 = __builtin_bit_cast(short8, (u32x4){w[0], w[1], w[2], w[3]});
  pa1 = __builtin_bit_cast(short8, (u32x4){w[4], w[5], w[6], w[7]});
}

__device__ __forceinline__ void head_epilogue(
    const f32x16 O[4], float lrun, int l5, int hi, float* cbufw,
    u16* __restrict__ obase)
{
  float ltot = lrun + __shfl_xor(lrun, 32);
  if (hi == 0) cbufw[l5] = ltot;
  float4 lv[4];
#pragma unroll
  for (int gg = 0; gg < 4; ++gg)
    lv[gg] = *reinterpret_cast<const float4*>(&cbufw[8 * gg + 4 * hi]);
#pragma unroll
  for (int r = 0; r < 16; ++r) {
    int crow = (r & 3) + 8 * (r >> 2) + 4 * hi;
    float inv = __builtin_amdgcn_rcpf((&lv[r >> 2].x)[r & 3]);
    u16* orow = obase + (size_t)crow * (HQ * DH) + l5;
#pragma unroll
    for (int n = 0; n < 4; ++n)
      orow[n * 32] = f2bf(O[n][r] * inv);
  }
}

__global__ __launch_bounds__(256, 2) void flash_attn_pipe_kernel(
    const u16* __restrict__ Qsrc, const u16* __restrict__ Kb,
    const u16* __restrict__ Vt, u16* __restrict__ ao,
    const float* __restrict__ ctab, const float* __restrict__ stab)
{
  const int tid = threadIdx.x;
  const int wave = tid >> 6;
  const int lane = tid & 63;
  const int l5 = lane & 31;
  const int hi = lane >> 5;

  const int bid = blockIdx.x;
  const int half = bid >> 8;
  const int u = (bid >> 3) & 31;
  const int x = bid & 7;
  const int c = x >> 1;
  const int hh = x & 1;
  const int b = c >> 1, kvh = c & 1;
  const int h = kvh * 8 + hh * 4 + wave;
  const int t = half ? u : (63 - u);
  const int q0 = 32 * t;
  const int nst = (t + 2) >> 1;          // 64-key steps
  const int bk = b * HKV + kvh;

  __shared__ u16 Ks[2][64 * 128];   // 32 KB; 16 slots/row, phys = slot^(key&15)
  __shared__ u16 Vs[2][128 * 64];   // 32 KB; 8 slots/row,  phys = slot^(d&7)
  __shared__ __align__(16) float cbuf[4][32];
  float* cbufw = cbuf[wave];

  const u16* Kg = Kb + (size_t)(b * L_) * (HKV * DH) + kvh * DH;
  const u16* Vg = Vt + (size_t)(bk * DH) * L_;

  auto stage = [&](int s) {
    const int buf = s & 1;
    const int j0 = s * 64;
#pragma unroll
    for (int q = 0; q < 4; ++q) {
      int cnk = q * 256 + tid;            // K chunk 0..1023
      int key = cnk >> 4, phys = cnk & 15;
      int slog = phys ^ (key & 15);
      const u16* src = Kg + (size_t)(j0 + key) * (HKV * DH) + slog * 8;
      __builtin_amdgcn_global_load_lds(GLB(src), LDS(&Ks[buf][(q * 256 + wave * 64) * 8]), 16, 0, 0);
    }
#pragma unroll
    for (int q = 0; q < 4; ++q) {
      int cnk = q * 256 + tid;            // V chunk 0..1023
      int d = cnk >> 3, phys = cnk & 7;
      int slog = phys ^ (d & 7);
      const u16* src = Vg + (size_t)d * L_ + j0 + slog * 8;
      __builtin_amdgcn_global_load_lds(GLB(src), LDS(&Vs[buf][(q * 256 + wave * 64) * 8]), 16, 0, 0);
    }
  };

  // ---- Q load from qkvb + in-register RoPE + scale (one-time) ----
  const u16* qrow = Qsrc + ((size_t)(b * L_ + q0 + l5)) * NQKV_ + h * DH + hi * 8;
  short8 qB[8];
#pragma unroll
  for (int ss = 0; ss < 8; ++ss)
    qB[ss] = *reinterpret_cast<const short8*>(qrow + ss * 16);
  {
    const float qscale = 0.08838834764831845f;  // 1/sqrt(128)
    const float* cb = ctab + (size_t)(q0 + l5) * 64 + hi * 8;
    const float* sb = stab + (size_t)(q0 + l5) * 64 + hi * 8;
#pragma unroll
    for (int ss = 0; ss < 4; ++ss) {
      float4 c0 = *reinterpret_cast<const float4*>(cb + ss * 16);
      float4 c1 = *reinterpret_cast<const float4*>(cb + ss * 16 + 4);
      float4 s0 = *reinterpret_cast<const float4*>(sb + ss * 16);
      float4 s1 = *reinterpret_cast<const float4*>(sb + ss * 16 + 4);
      float cj[8] = {c0.x, c0.y, c0.z, c0.w, c1.x, c1.y, c1.z, c1.w};
      float sj[8] = {s0.x, s0.y, s0.z, s0.w, s1.x, s1.y, s1.z, s1.w};
#pragma unroll
      for (int j = 0; j < 8; ++j) {
        float x1 = bf2f((u16)qB[ss][j]);
        float x2 = bf2f((u16)qB[ss + 4][j]);
        qB[ss][j]     = (short)f2bf((x1 * cj[j] - x2 * sj[j]) * qscale);
        qB[ss + 4][j] = (short)f2bf((x2 * cj[j] + x1 * sj[j]) * qscale);
      }
    }
  }

  f32x16 O[4];
#pragma unroll
  for (int n = 0; n < 4; ++n)
#pragma unroll
    for (int r = 0; r < 16; ++r) O[n][r] = 0.f;
  float mrun = -INFINITY, lrun = 0.f;

  stage(0);
  if (nst > 1) stage(1);

#pragma unroll 1
  for (int s = 0; s < nst; ++s) {
    if (s + 1 < nst) { asm volatile("s_waitcnt vmcnt(8)" ::: "memory"); }
    else             { asm volatile("s_waitcnt vmcnt(0)" ::: "memory"); }
    __builtin_amdgcn_s_barrier();          // buf[s&1] landed for all waves
    __builtin_amdgcn_sched_barrier(0);

    const int cur = s & 1;
    const int j0 = s * 64;
    const int kx = l5 & 15;

    // subtile A: keys j0 + 0..31
    short8 kcA[8], vvA[8];
#pragma unroll
    for (int ss = 0; ss < 8; ++ss) {
      int phys = (2 * ss + hi) ^ kx;
      kcA[ss] = *reinterpret_cast<const short8*>(&Ks[cur][l5 * 128 + phys * 8]);
    }
#pragma unroll
    for (int n = 0; n < 4; ++n) {
#pragma unroll
      for (int cc = 0; cc < 2; ++cc) {
        int d = n * 32 + l5;
        int phys = (cc * 2 + hi) ^ (d & 7);
        vvA[n * 2 + cc] = *reinterpret_cast<const short8*>(&Vs[cur][d * 64 + phys * 8]);
      }
    }
    f32x16 Sa;
#pragma unroll
    for (int r = 0; r < 16; ++r) Sa[r] = 0.f;
#pragma unroll
    for (int ss = 0; ss < 8; ++ss)
      Sa = __builtin_amdgcn_mfma_f32_32x32x16_bf16(kcA[ss], qB[ss], Sa, 0, 0, 0);

    // subtile B: keys j0 + 32..63
    short8 kcB[8], vvB[8];
#pragma unroll
    for (int ss = 0; ss < 8; ++ss) {
      int phys = (2 * ss + hi) ^ kx;
      kcB[ss] = *reinterpret_cast<const short8*>(&Ks[cur][(32 + l5) * 128 + phys * 8]);
    }
#pragma unroll
    for (int n = 0; n < 4; ++n) {
#pragma unroll
      for (int cc = 0; cc < 2; ++cc) {
        int d = n * 32 + l5;
        int phys = (4 + cc * 2 + hi) ^ (d & 7);
        vvB[n * 2 + cc] = *reinterpret_cast<const short8*>(&Vs[cur][d * 64 + phys * 8]);
      }
    }
    f32x16 Sb;
#pragma unroll
    for (int r = 0; r < 16; ++r) Sb[r] = 0.f;
#pragma unroll
    for (int ss = 0; ss < 8; ++ss)
      Sb = __builtin_amdgcn_mfma_f32_32x32x16_bf16(kcB[ss], qB[ss], Sb, 0, 0, 0);

    asm volatile("s_waitcnt lgkmcnt(0)" ::: "memory");
    __builtin_amdgcn_sched_barrier(0);
    __builtin_amdgcn_s_barrier();          // all waves done reading buf[cur]
    if (s + 2 < nst) stage(s + 2);         // overwrite buf[cur] for step s+2

    float sa[16], sb[16];
#pragma unroll
    for (int r = 0; r < 16; ++r) { sa[r] = Sa[r]; sb[r] = Sb[r]; }

    // causal masks
    if (j0 == q0) {
#pragma unroll
      for (int r = 0; r < 16; ++r) {
        int crow = (r & 3) + 8 * (r >> 2) + 4 * hi;
        if (crow > l5) sa[r] = -INFINITY;
        sb[r] = -INFINITY;                 // keys q0+32.. all beyond queries
      }
    } else if (j0 + 32 == q0) {
#pragma unroll
      for (int r = 0; r < 16; ++r) {
        int crow = (r & 3) + 8 * (r >> 2) + 4 * hi;
        if (crow > l5) sb[r] = -INFINITY;
      }
    }

    // row max over 64 keys: in-register trees + one cross-half exchange
    float t8[8], t4[4];
#pragma unroll
    for (int r = 0; r < 8; ++r) t8[r] = fmaxf(fmaxf(sa[2 * r], sa[2 * r + 1]),
                                              fmaxf(sb[2 * r], sb[2 * r + 1]));
#pragma unroll
    for (int r = 0; r < 4; ++r) t4[r] = fmaxf(t8[2 * r], t8[2 * r + 1]);
    float pmax = fmaxf(fmaxf(t4[0], t4[1]), fmaxf(t4[2], t4[3]));
    pmax = fmaxf(pmax, __shfl_xor(pmax, 32));

    // defer-max rescale (T13)
    if (__any(pmax > mrun + 8.0f)) {
      float mnew = fmaxf(mrun, pmax);
      float corr = __expf(mrun - mnew);
      mrun = mnew;
      lrun *= corr;
      if (hi == 0) cbufw[l5] = corr;
      float4 cr[4];
#pragma unroll
      for (int g = 0; g < 4; ++g)
        cr[g] = *reinterpret_cast<const float4*>(&cbufw[8 * g + 4 * hi]);
#pragma unroll
      for (int n = 0; n < 4; ++n)
#pragma unroll
        for (int r = 0; r < 16; ++r)
          O[n][r] *= (&cr[r >> 2].x)[r & 3];
    }

    // P = exp(S - m); per-half partial sum (cross-half merge at epilogue)
    float pa_[16], pb_[16];
#pragma unroll
    for (int r = 0; r < 16; ++r) {
      pa_[r] = __expf(sa[r] - mrun);
      pb_[r] = __expf(sb[r] - mrun);
    }
#pragma unroll
    for (int r = 0; r < 8; ++r) t8[r] = (pa_[2 * r] + pa_[2 * r + 1]) +
                                        (pb_[2 * r] + pb_[2 * r + 1]);
#pragma unroll
    for (int r = 0; r < 4; ++r) t4[r] = t8[2 * r] + t8[2 * r + 1];
    lrun += (t4[0] + t4[1]) + (t4[2] + t4[3]);

    // pack P -> A-fragments (T12)
    short8 paA0, paA1, paB0, paB1;
    pack16(pa_, paA0, paA1);
    pack16(pb_, paB0, paB1);

    // O += P V (4 k-slots of 16)
#pragma unroll
    for (int n = 0; n < 4; ++n) {
      O[n] = __builtin_amdgcn_mfma_f32_32x32x16_bf16(paA0, vvA[n * 2 + 0], O[n], 0, 0, 0);
      O[n] = __builtin_amdgcn_mfma_f32_32x32x16_bf16(paA1, vvA[n * 2 + 1], O[n], 0, 0, 0);
      O[n] = __builtin_amdgcn_mfma_f32_32x32x16_bf16(paB0, vvB[n * 2 + 0], O[n], 0, 0, 0);
      O[n] = __builtin_amdgcn_mfma_f32_32x32x16_bf16(paB1, vvB[n * 2 + 1], O[n], 0, 0, 0);
    }
  }

  u16* obase = ao + (size_t)(b * L_ + q0) * (HQ * DH) + h * DH;
  head_epilogue(O, lrun, l5, hi, cbufw, obase);
}

// ---------------------------------------------------------------------------
// launch
// ---------------------------------------------------------------------------
extern "C" void kernel_launch(void* const* d_in, const int* in_sizes, int n_in,
                              void* d_out, int out_size, void* d_ws, size_t ws_size,
                              hipStream_t stream) {
  const float* x  = (const float*)d_in[0];
  const float* wq = (const float*)d_in[1];
  const float* wk = (const float*)d_in[2];
  const float* wv = (const float*)d_in[3];
  const float* wo = (const float*)d_in[4];
  const float* bq = (const float*)d_in[5];
  const float* bk = (const float*)d_in[6];
  const float* bv = (const float*)d_in[7];
  float* out = (float*)d_out;

  const int M = B_ * L_;
  const int NQKV = NQKV_;                       // 2560
  const size_t QN = (size_t)B_ * L_ * HQ * DH;  // 8388608
  const size_t KN = (size_t)B_ * L_ * HKV * DH; // 1048576
  const size_t TN = (size_t)L_ * (DH / 2);      // 131072

  float* ws = (float*)d_ws;
  float* ct   = ws;
  float* st   = ct + TN;
  float* bqkv = st + TN;
  u16* qkvb   = (u16*)(bqkv + NQKV);        // bf16 QKV projection output
  u16* xb     = qkvb + (size_t)M * NQKV;    // x bf16
  u16* wqkvb  = xb + (size_t)M * E_;
  u16* ao     = wqkvb + (size_t)NQKV * E_;  // attention output (bf16)
  u16* Kbf    = ao + QN;
  u16* Vt     = Kbf + KN;
  u16* wob    = Vt + KN;                    // wo bf16 (own slot; converted early)

  rope_tab_kernel<<<(L_ * (DH / 2) + 255) / 256, 256, 0, stream>>>(ct, st);

  cvt_bf16_kernel<<<(int)(QN / 8 / 256), 256, 0, stream>>>(x, xb, (int)QN);
  // all 4 weights in one launch (wq|wk|wv -> wqkvb, wo -> wob)
  cvt4_bf16_kernel<<<((NQKV + E_) * E_) / 8 / 256, 256, 0, stream>>>(
      wq, wk, wv, wo, wqkvb, wob,
      HQ * DH * E_, HKV * DH * E_, HKV * DH * E_, E_ * E_);
  bias_concat_kernel<<<(NQKV + 255) / 256, 256, 0, stream>>>(bq, bk, bv, bqkv);

  // fused QKV projection: [4096][2560] bf16 (grid 640, XCD-swizzled 1D)
  gemm_bf16_kernel<true><<<dim3((NQKV / GBN) * (M / GBM)), 256, 0, stream>>>(
      xb, wqkvb, bqkv, qkvb, M, NQKV, E_);

  // fused K-rope + V-transpose (one launch)
  kv_prep_kernel<<<dim3(KROPE_BLKS + 256), 256, 0, stream>>>(
      qkvb, Kbf, Vt, ct, st);

  flash_attn_pipe_kernel<<<dim3(512), 256, 0, stream>>>(
      qkvb, Kbf, Vt, ao, ct, st);

  // O-projection (grid 512, XCD-swizzled 1D)
  gemm_bf16_kernel<false><<<dim3((E_ / GBN) * (M / GBM)), 256, 0, stream>>>(
      ao, wob, nullptr, out, M, E_, E_);
}

// Round 22
// 187.430 us; speedup vs baseline: 1.3828x; 1.0030x over previous
//
#include <hip/hip_runtime.h>
#include <math.h>

#define B_ 2
#define L_ 2048
#define E_ 2048
#define HQ 16
#define HKV 2
#define DH 128
#define NQKV_ 2560

typedef unsigned short u16;
typedef unsigned int u32;
typedef __attribute__((ext_vector_type(8))) short short8;
typedef __attribute__((ext_vector_type(4))) float f32x4;
typedef __attribute__((ext_vector_type(16))) float f32x16;
typedef __attribute__((ext_vector_type(4))) u32 u32x4;

static __device__ __forceinline__ u16 f2bf(float f) {
  unsigned int u = __float_as_uint(f);
  unsigned int r = (u + 0x7fffu + ((u >> 16) & 1u)) >> 16;
  return (u16)r;
}
static __device__ __forceinline__ float bf2f(u16 v) {
  return __uint_as_float(((u32)v) << 16);
}

static __device__ __forceinline__ u32 cvt_pk_bf16(float lo, float hi) {
  u32 r;
  asm volatile("v_cvt_pk_bf16_f32 %0, %1, %2" : "=v"(r) : "v"(lo), "v"(hi));
  return r;
}
// swaps a's upper-half lanes with b's lower-half lanes (gfx950).
static __device__ __forceinline__ void permswap(u32& a, u32& b) {
  asm volatile("v_permlane32_swap_b32 %0, %1" : "+v"(a), "+v"(b));
}

#define GLB(p) ((const __attribute__((address_space(1))) void*)(p))
#define LDS(p) ((__attribute__((address_space(3))) void*)(p))

// ---------------------------------------------------------------------------
// fp32 -> bf16 convert
// ---------------------------------------------------------------------------
__global__ void cvt_bf16_kernel(const float* __restrict__ in,
                                u16* __restrict__ out, int n) {
  int i = (blockIdx.x * 256 + threadIdx.x) * 8;
  if (i >= n) return;
  float4 a = *reinterpret_cast<const float4*>(in + i);
  float4 b = *reinterpret_cast<const float4*>(in + i + 4);
  short8 r;
  r[0] = (short)f2bf(a.x); r[1] = (short)f2bf(a.y);
  r[2] = (short)f2bf(a.z); r[3] = (short)f2bf(a.w);
  r[4] = (short)f2bf(b.x); r[5] = (short)f2bf(b.y);
  r[6] = (short)f2bf(b.z); r[7] = (short)f2bf(b.w);
  *reinterpret_cast<short8*>(out + i) = r;
}

// ---------------------------------------------------------------------------
// fused wq|wk|wv -> wqkvb  and  wo -> wob, one launch.
// ---------------------------------------------------------------------------
__global__ void cvt4_bf16_kernel(const float* __restrict__ w0,
                                 const float* __restrict__ w1,
                                 const float* __restrict__ w2,
                                 const float* __restrict__ w3,
                                 u16* __restrict__ out012,
                                 u16* __restrict__ out3,
                                 int n0, int n1, int n2, int n3) {
  int i = (blockIdx.x * 256 + threadIdx.x) * 8;
  const float* src;
  u16* dst;
  int off;
  if (i < n0) { src = w0; dst = out012; off = i; }
  else if (i < n0 + n1) { src = w1; dst = out012; off = i - n0; }
  else if (i < n0 + n1 + n2) { src = w2; dst = out012; off = i - n0 - n1; }
  else if (i < n0 + n1 + n2 + n3) { src = w3; dst = out3; off = i - n0 - n1 - n2; }
  else return;
  int dsti = (dst == out3) ? off : i;
  float4 a = *reinterpret_cast<const float4*>(src + off);
  float4 b = *reinterpret_cast<const float4*>(src + off + 4);
  short8 r;
  r[0] = (short)f2bf(a.x); r[1] = (short)f2bf(a.y);
  r[2] = (short)f2bf(a.z); r[3] = (short)f2bf(a.w);
  r[4] = (short)f2bf(b.x); r[5] = (short)f2bf(b.y);
  r[6] = (short)f2bf(b.z); r[7] = (short)f2bf(b.w);
  *reinterpret_cast<short8*>(dst + dsti) = r;
}

// ---------------------------------------------------------------------------
// bias concat
// ---------------------------------------------------------------------------
__global__ void bias_concat_kernel(const float* __restrict__ bq,
                                   const float* __restrict__ bk,
                                   const float* __restrict__ bv,
                                   float* __restrict__ dst) {
  int i = blockIdx.x * 256 + threadIdx.x;
  if (i >= NQKV_) return;
  float v;
  if (i < HQ * DH) v = bq[i];
  else if (i < HQ * DH + HKV * DH) v = bk[i - HQ * DH];
  else v = bv[i - HQ * DH - HKV * DH];
  dst[i] = v;
}

// ---------------------------------------------------------------------------
// RoPE table
// ---------------------------------------------------------------------------
__global__ void rope_tab_kernel(float* __restrict__ ctab, float* __restrict__ stab) {
  int idx = blockIdx.x * 256 + threadIdx.x;
  if (idx >= L_ * (DH / 2)) return;
  int pos = idx >> 6;
  int f = idx & 63;
  float inv_freq = powf(10000.0f, -(float)f * (1.0f / 64.0f));
  float ang = (float)pos * inv_freq;
  float s, c;
  sincosf(ang, &s, &c);
  ctab[idx] = c;
  stab[idx] = s;
}

// ---------------------------------------------------------------------------
// fused K-rope + V-transpose from bf16 qkv buffer (block-granular split).
// ---------------------------------------------------------------------------
#define KROPE_BLKS (B_ * L_ * HKV * 64 / 256)   // 2048

__global__ __launch_bounds__(256) void kv_prep_kernel(
    const u16* __restrict__ qkv, u16* __restrict__ Kbf, u16* __restrict__ Vt,
    const float* __restrict__ ctab, const float* __restrict__ stab) {
  __shared__ u16 tile[64][68];
  if (blockIdx.x < KROPE_BLKS) {
    int idx = blockIdx.x * 256 + threadIdx.x;
    int f = idx & 63;
    int row = idx >> 6;          // (b*L+l)*HKV + h
    int h = row % HKV;
    int bl = row / HKV;
    int l = bl & (L_ - 1);
    size_t sbase = (size_t)bl * NQKV_ + HQ * DH + (size_t)h * DH;
    size_t dbase = (size_t)bl * ((size_t)HKV * DH) + (size_t)h * DH;
    float x1 = bf2f(qkv[sbase + f]);
    float x2 = bf2f(qkv[sbase + 64 + f]);
    float c = ctab[l * 64 + f];
    float s = stab[l * 64 + f];
    Kbf[dbase + f]      = f2bf(x1 * c - x2 * s);
    Kbf[dbase + 64 + f] = f2bf(x2 * c + x1 * s);
    return;
  }
  // V transpose
  const int vb = blockIdx.x - KROPE_BLKS;   // 0..255
  const int k0 = (vb & 31) * 64;
  const int d0 = ((vb >> 5) & 1) * 64;
  const int bk = vb >> 6;                   // b*HKV + kvh
  const int b = bk / HKV, kvh = bk % HKV;
  const int colOff = HQ * DH + HKV * DH;
#pragma unroll
  for (int i = 0; i < 4; ++i) {
    int key = i * 16 + (threadIdx.x >> 4);
    int d4 = (threadIdx.x & 15) * 4;
    *reinterpret_cast<ushort2*>(&tile[key][d4]) = *reinterpret_cast<const ushort2*>(
        &qkv[(size_t)(b * L_ + k0 + key) * NQKV_ + colOff + kvh * DH + d0 + d4]);
    *reinterpret_cast<ushort2*>(&tile[key][d4 + 2]) = *reinterpret_cast<const ushort2*>(
        &qkv[(size_t)(b * L_ + k0 + key) * NQKV_ + colOff + kvh * DH + d0 + d4 + 2]);
  }
  __syncthreads();
  const int d = threadIdx.x >> 2;
  const int kq = (threadIdx.x & 3) * 16;
  u16* orow = Vt + ((size_t)(bk * DH + d0 + d)) * L_ + k0 + kq;
#pragma unroll
  for (int j = 0; j < 16; ++j) orow[j] = tile[kq + j][d];
}

// ---------------------------------------------------------------------------
// bf16 MFMA GEMM: 128x128 tile, BK=64, DOUBLE-BUFFERED LDS with counted
// vmcnt pipeline (attention-proven R9 recipe), XOR-slot mapping
// (R14/R15-proven coalesced staging), bijective XCD swizzle.
// Per step: {vmcnt(8); barrier; 16x ds_read_b128; lgkmcnt(0); barrier;
// stage(s+2); 32 MFMA}. Loads never drain to 0 mid-loop.
// ---------------------------------------------------------------------------
#define GBM 128
#define GBN 128
#define GBK 64

template <bool BF16OUT>
__global__ __launch_bounds__(256) void gemm_bf16_kernel(
    const u16* __restrict__ A, const u16* __restrict__ W,
    const float* __restrict__ bias, void* __restrict__ Cv,
    int M, int N, int K)
{
  __shared__ u16 As[2][GBM * GBK];   // 16 KB each
  __shared__ u16 Bs[2][GBN * GBK];   // 16 KB each

  const int tid = threadIdx.x;
  const int wave = tid >> 6;
  const int lane = tid & 63;
  const int lr = lane & 15;
  const int lg = lane >> 4;

  // bijective XCD-chunked swizzle (nwg % 8 == 0)
  const int nwg = gridDim.x;
  const int qch = nwg >> 3;
  const int bid = blockIdx.x;
  const int wgid = (bid & 7) * qch + (bid >> 3);
  const int nx = N / GBN;
  const int bm = (wgid / nx) * GBM;
  const int bn = (wgid % nx) * GBN;

  const int wm = (wave >> 1) * 64;
  const int wn = (wave & 1) * 64;

  f32x4 acc[4][4];
#pragma unroll
  for (int i = 0; i < 4; ++i)
#pragma unroll
    for (int j = 0; j < 4; ++j) acc[i][j] = (f32x4){0.f, 0.f, 0.f, 0.f};

  const u16* gA[4];
  const u16* gB[4];
#pragma unroll
  for (int t = 0; t < 4; ++t) {
    int c = t * 256 + wave * 64 + lane;
    int row = c >> 3;
    int slog = (c & 7) ^ (row & 7);
    gA[t] = A + (size_t)(bm + row) * K + slog * 8;
    gB[t] = W + (size_t)(bn + row) * K + slog * 8;
  }

  const int nk = K / GBK;
  auto stage = [&](int s) {
    const int buf = s & 1;
    const int k0 = s * GBK;
#pragma unroll
    for (int t = 0; t < 4; ++t) {
      __builtin_amdgcn_global_load_lds(GLB(gA[t] + k0),
          LDS(&As[buf][(t * 256 + wave * 64) * 8]), 16, 0, 0);
      __builtin_amdgcn_global_load_lds(GLB(gB[t] + k0),
          LDS(&Bs[buf][(t * 256 + wave * 64) * 8]), 16, 0, 0);
    }
  };

  const int fx = lr & 7;

  stage(0);
  stage(1);

#pragma unroll 1
  for (int s = 0; s < nk; ++s) {
    if (s + 1 < nk) { asm volatile("s_waitcnt vmcnt(8)" ::: "memory"); }
    else            { asm volatile("s_waitcnt vmcnt(0)" ::: "memory"); }
    __builtin_amdgcn_s_barrier();          // buf[s&1] landed for all waves
    __builtin_amdgcn_sched_barrier(0);

    const int cur = s & 1;
    short8 af[2][4], bf[2][4];
#pragma unroll
    for (int kk = 0; kk < 2; ++kk) {
#pragma unroll
      for (int mi = 0; mi < 4; ++mi) {
        int row = wm + mi * 16 + lr;
        int slot = (kk * 4 + lg) ^ fx;
        af[kk][mi] = *reinterpret_cast<const short8*>(&As[cur][row * 64 + slot * 8]);
      }
#pragma unroll
      for (int ni = 0; ni < 4; ++ni) {
        int row = wn + ni * 16 + lr;
        int slot = (kk * 4 + lg) ^ fx;
        bf[kk][ni] = *reinterpret_cast<const short8*>(&Bs[cur][row * 64 + slot * 8]);
      }
    }
    asm volatile("s_waitcnt lgkmcnt(0)" ::: "memory");
    __builtin_amdgcn_sched_barrier(0);
    __builtin_amdgcn_s_barrier();          // all waves done reading buf[cur]
    if (s + 2 < nk) stage(s + 2);          // overwrite buf[cur] for step s+2

#pragma unroll
    for (int kk = 0; kk < 2; ++kk)
#pragma unroll
      for (int mi = 0; mi < 4; ++mi)
#pragma unroll
        for (int ni = 0; ni < 4; ++ni)
          acc[mi][ni] = __builtin_amdgcn_mfma_f32_16x16x32_bf16(
              af[kk][mi], bf[kk][ni], acc[mi][ni], 0, 0, 0);
  }

#pragma unroll
  for (int ni = 0; ni < 4; ++ni) {
    int col = bn + wn + ni * 16 + lr;
    float bv = (bias != nullptr) ? bias[col] : 0.f;
#pragma unroll
    for (int mi = 0; mi < 4; ++mi) {
#pragma unroll
      for (int r = 0; r < 4; ++r) {
        int row = bm + wm + mi * 16 + lg * 4 + r;
        float val = acc[mi][ni][r] + bv;
        if constexpr (BF16OUT)
          ((u16*)Cv)[(size_t)row * N + col] = f2bf(val);
        else
          ((float*)Cv)[(size_t)row * N + col] = val;
      }
    }
  }
}

// ---------------------------------------------------------------------------
// Flash attention (R16/R19-proven structure) + fused in-register Q RoPE.
// KVBLK=64, 4-wave blocks (4 heads), K+V LDS double-buffered, counted-vmcnt
// pipeline. Grid 512 = 2 blocks/CU (blocks i, i+256 carry tiles 63-u and u).
// ---------------------------------------------------------------------------
__device__ __forceinline__ void pack16(const float p[16], short8& pa0, short8& pa1) {
  u32 w[8];
#pragma unroll
  for (int t = 0; t < 8; ++t) w[t] = cvt_pk_bf16(p[2 * t], p[2 * t + 1]);
  permswap(w[0], w[2]); permswap(w[1], w[3]);
  permswap(w[4], w[6]); permswap(w[5], w[7]);
  pa0 = __builtin_bit_cast(short8, (u32x4){w[0], w[1], w[2], w[3]});
  pa1 = __builtin_bit_cast(short8, (u32x4){w[4], w[5], w[6], w[7]});
}

__device__ __forceinline__ void head_epilogue(
    const f32x16 O[4], float lrun, int l5, int hi, float* cbufw,
    u16* __restrict__ obase)
{
  float ltot = lrun + __shfl_xor(lrun, 32);
  if (hi == 0) cbufw[l5] = ltot;
  float4 lv[4];
#pragma unroll
  for (int gg = 0; gg < 4; ++gg)
    lv[gg] = *reinterpret_cast<const float4*>(&cbufw[8 * gg + 4 * hi]);
#pragma unroll
  for (int r = 0; r < 16; ++r) {
    int crow = (r & 3) + 8 * (r >> 2) + 4 * hi;
    float inv = __builtin_amdgcn_rcpf((&lv[r >> 2].x)[r & 3]);
    u16* orow = obase + (size_t)crow * (HQ * DH) + l5;
#pragma unroll
    for (int n = 0; n < 4; ++n)
      orow[n * 32] = f2bf(O[n][r] * inv);
  }
}

__global__ __launch_bounds__(256, 2) void flash_attn_pipe_kernel(
    const u16* __restrict__ Qsrc, const u16* __restrict__ Kb,
    const u16* __restrict__ Vt, u16* __restrict__ ao,
    const float* __restrict__ ctab, const float* __restrict__ stab)
{
  const int tid = threadIdx.x;
  const int wave = tid >> 6;
  const int lane = tid & 63;
  const int l5 = lane & 31;
  const int hi = lane >> 5;

  const int bid = blockIdx.x;
  const int half = bid >> 8;
  const int u = (bid >> 3) & 31;
  const int x = bid & 7;
  const int c = x >> 1;
  const int hh = x & 1;
  const int b = c >> 1, kvh = c & 1;
  const int h = kvh * 8 + hh * 4 + wave;
  const int t = half ? u : (63 - u);
  const int q0 = 32 * t;
  const int nst = (t + 2) >> 1;          // 64-key steps
  const int bk = b * HKV + kvh;

  __shared__ u16 Ks[2][64 * 128];   // 32 KB; 16 slots/row, phys = slot^(key&15)
  __shared__ u16 Vs[2][128 * 64];   // 32 KB; 8 slots/row,  phys = slot^(d&7)
  __shared__ __align__(16) float cbuf[4][32];
  float* cbufw = cbuf[wave];

  const u16* Kg = Kb + (size_t)(b * L_) * (HKV * DH) + kvh * DH;
  const u16* Vg = Vt + (size_t)(bk * DH) * L_;

  auto stage = [&](int s) {
    const int buf = s & 1;
    const int j0 = s * 64;
#pragma unroll
    for (int q = 0; q < 4; ++q) {
      int cnk = q * 256 + tid;            // K chunk 0..1023
      int key = cnk >> 4, phys = cnk & 15;
      int slog = phys ^ (key & 15);
      const u16* src = Kg + (size_t)(j0 + key) * (HKV * DH) + slog * 8;
      __builtin_amdgcn_global_load_lds(GLB(src), LDS(&Ks[buf][(q * 256 + wave * 64) * 8]), 16, 0, 0);
    }
#pragma unroll
    for (int q = 0; q < 4; ++q) {
      int cnk = q * 256 + tid;            // V chunk 0..1023
      int d = cnk >> 3, phys = cnk & 7;
      int slog = phys ^ (d & 7);
      const u16* src = Vg + (size_t)d * L_ + j0 + slog * 8;
      __builtin_amdgcn_global_load_lds(GLB(src), LDS(&Vs[buf][(q * 256 + wave * 64) * 8]), 16, 0, 0);
    }
  };

  // ---- Q load from qkvb + in-register RoPE + scale (one-time) ----
  const u16* qrow = Qsrc + ((size_t)(b * L_ + q0 + l5)) * NQKV_ + h * DH + hi * 8;
  short8 qB[8];
#pragma unroll
  for (int ss = 0; ss < 8; ++ss)
    qB[ss] = *reinterpret_cast<const short8*>(qrow + ss * 16);
  {
    const float qscale = 0.08838834764831845f;  // 1/sqrt(128)
    const float* cb = ctab + (size_t)(q0 + l5) * 64 + hi * 8;
    const float* sb = stab + (size_t)(q0 + l5) * 64 + hi * 8;
#pragma unroll
    for (int ss = 0; ss < 4; ++ss) {
      float4 c0 = *reinterpret_cast<const float4*>(cb + ss * 16);
      float4 c1 = *reinterpret_cast<const float4*>(cb + ss * 16 + 4);
      float4 s0 = *reinterpret_cast<const float4*>(sb + ss * 16);
      float4 s1 = *reinterpret_cast<const float4*>(sb + ss * 16 + 4);
      float cj[8] = {c0.x, c0.y, c0.z, c0.w, c1.x, c1.y, c1.z, c1.w};
      float sj[8] = {s0.x, s0.y, s0.z, s0.w, s1.x, s1.y, s1.z, s1.w};
#pragma unroll
      for (int j = 0; j < 8; ++j) {
        float x1 = bf2f((u16)qB[ss][j]);
        float x2 = bf2f((u16)qB[ss + 4][j]);
        qB[ss][j]     = (short)f2bf((x1 * cj[j] - x2 * sj[j]) * qscale);
        qB[ss + 4][j] = (short)f2bf((x2 * cj[j] + x1 * sj[j]) * qscale);
      }
    }
  }

  f32x16 O[4];
#pragma unroll
  for (int n = 0; n < 4; ++n)
#pragma unroll
    for (int r = 0; r < 16; ++r) O[n][r] = 0.f;
  float mrun = -INFINITY, lrun = 0.f;

  stage(0);
  if (nst > 1) stage(1);

#pragma unroll 1
  for (int s = 0; s < nst; ++s) {
    if (s + 1 < nst) { asm volatile("s_waitcnt vmcnt(8)" ::: "memory"); }
    else             { asm volatile("s_waitcnt vmcnt(0)" ::: "memory"); }
    __builtin_amdgcn_s_barrier();          // buf[s&1] landed for all waves
    __builtin_amdgcn_sched_barrier(0);

    const int cur = s & 1;
    const int j0 = s * 64;
    const int kx = l5 & 15;

    // subtile A: keys j0 + 0..31
    short8 kcA[8], vvA[8];
#pragma unroll
    for (int ss = 0; ss < 8; ++ss) {
      int phys = (2 * ss + hi) ^ kx;
      kcA[ss] = *reinterpret_cast<const short8*>(&Ks[cur][l5 * 128 + phys * 8]);
    }
#pragma unroll
    for (int n = 0; n < 4; ++n) {
#pragma unroll
      for (int cc = 0; cc < 2; ++cc) {
        int d = n * 32 + l5;
        int phys = (cc * 2 + hi) ^ (d & 7);
        vvA[n * 2 + cc] = *reinterpret_cast<const short8*>(&Vs[cur][d * 64 + phys * 8]);
      }
    }
    f32x16 Sa;
#pragma unroll
    for (int r = 0; r < 16; ++r) Sa[r] = 0.f;
#pragma unroll
    for (int ss = 0; ss < 8; ++ss)
      Sa = __builtin_amdgcn_mfma_f32_32x32x16_bf16(kcA[ss], qB[ss], Sa, 0, 0, 0);

    // subtile B: keys j0 + 32..63
    short8 kcB[8], vvB[8];
#pragma unroll
    for (int ss = 0; ss < 8; ++ss) {
      int phys = (2 * ss + hi) ^ kx;
      kcB[ss] = *reinterpret_cast<const short8*>(&Ks[cur][(32 + l5) * 128 + phys * 8]);
    }
#pragma unroll
    for (int n = 0; n < 4; ++n) {
#pragma unroll
      for (int cc = 0; cc < 2; ++cc) {
        int d = n * 32 + l5;
        int phys = (4 + cc * 2 + hi) ^ (d & 7);
        vvB[n * 2 + cc] = *reinterpret_cast<const short8*>(&Vs[cur][d * 64 + phys * 8]);
      }
    }
    f32x16 Sb;
#pragma unroll
    for (int r = 0; r < 16; ++r) Sb[r] = 0.f;
#pragma unroll
    for (int ss = 0; ss < 8; ++ss)
      Sb = __builtin_amdgcn_mfma_f32_32x32x16_bf16(kcB[ss], qB[ss], Sb, 0, 0, 0);

    asm volatile("s_waitcnt lgkmcnt(0)" ::: "memory");
    __builtin_amdgcn_sched_barrier(0);
    __builtin_amdgcn_s_barrier();          // all waves done reading buf[cur]
    if (s + 2 < nst) stage(s + 2);         // overwrite buf[cur] for step s+2

    float sa[16], sb[16];
#pragma unroll
    for (int r = 0; r < 16; ++r) { sa[r] = Sa[r]; sb[r] = Sb[r]; }

    // causal masks
    if (j0 == q0) {
#pragma unroll
      for (int r = 0; r < 16; ++r) {
        int crow = (r & 3) + 8 * (r >> 2) + 4 * hi;
        if (crow > l5) sa[r] = -INFINITY;
        sb[r] = -INFINITY;                 // keys q0+32.. all beyond queries
      }
    } else if (j0 + 32 == q0) {
#pragma unroll
      for (int r = 0; r < 16; ++r) {
        int crow = (r & 3) + 8 * (r >> 2) + 4 * hi;
        if (crow > l5) sb[r] = -INFINITY;
      }
    }

    // row max over 64 keys: in-register trees + one cross-half exchange
    float t8[8], t4[4];
#pragma unroll
    for (int r = 0; r < 8; ++r) t8[r] = fmaxf(fmaxf(sa[2 * r], sa[2 * r + 1]),
                                              fmaxf(sb[2 * r], sb[2 * r + 1]));
#pragma unroll
    for (int r = 0; r < 4; ++r) t4[r] = fmaxf(t8[2 * r], t8[2 * r + 1]);
    float pmax = fmaxf(fmaxf(t4[0], t4[1]), fmaxf(t4[2], t4[3]));
    pmax = fmaxf(pmax, __shfl_xor(pmax, 32));

    // defer-max rescale (T13)
    if (__any(pmax > mrun + 8.0f)) {
      float mnew = fmaxf(mrun, pmax);
      float corr = __expf(mrun - mnew);
      mrun = mnew;
      lrun *= corr;
      if (hi == 0) cbufw[l5] = corr;
      float4 cr[4];
#pragma unroll
      for (int g = 0; g < 4; ++g)
        cr[g] = *reinterpret_cast<const float4*>(&cbufw[8 * g + 4 * hi]);
#pragma unroll
      for (int n = 0; n < 4; ++n)
#pragma unroll
        for (int r = 0; r < 16; ++r)
          O[n][r] *= (&cr[r >> 2].x)[r & 3];
    }

    // P = exp(S - m); per-half partial sum (cross-half merge at epilogue)
    float pa_[16], pb_[16];
#pragma unroll
    for (int r = 0; r < 16; ++r) {
      pa_[r] = __expf(sa[r] - mrun);
      pb_[r] = __expf(sb[r] - mrun);
    }
#pragma unroll
    for (int r = 0; r < 8; ++r) t8[r] = (pa_[2 * r] + pa_[2 * r + 1]) +
                                        (pb_[2 * r] + pb_[2 * r + 1]);
#pragma unroll
    for (int r = 0; r < 4; ++r) t4[r] = t8[2 * r] + t8[2 * r + 1];
    lrun += (t4[0] + t4[1]) + (t4[2] + t4[3]);

    // pack P -> A-fragments (T12)
    short8 paA0, paA1, paB0, paB1;
    pack16(pa_, paA0, paA1);
    pack16(pb_, paB0, paB1);

    // O += P V (4 k-slots of 16)
#pragma unroll
    for (int n = 0; n < 4; ++n) {
      O[n] = __builtin_amdgcn_mfma_f32_32x32x16_bf16(paA0, vvA[n * 2 + 0], O[n], 0, 0, 0);
      O[n] = __builtin_amdgcn_mfma_f32_32x32x16_bf16(paA1, vvA[n * 2 + 1], O[n], 0, 0, 0);
      O[n] = __builtin_amdgcn_mfma_f32_32x32x16_bf16(paB0, vvB[n * 2 + 0], O[n], 0, 0, 0);
      O[n] = __builtin_amdgcn_mfma_f32_32x32x16_bf16(paB1, vvB[n * 2 + 1], O[n], 0, 0, 0);
    }
  }

  u16* obase = ao + (size_t)(b * L_ + q0) * (HQ * DH) + h * DH;
  head_epilogue(O, lrun, l5, hi, cbufw, obase);
}

// ---------------------------------------------------------------------------
// launch
// ---------------------------------------------------------------------------
extern "C" void kernel_launch(void* const* d_in, const int* in_sizes, int n_in,
                              void* d_out, int out_size, void* d_ws, size_t ws_size,
                              hipStream_t stream) {
  const float* x  = (const float*)d_in[0];
  const float* wq = (const float*)d_in[1];
  const float* wk = (const float*)d_in[2];
  const float* wv = (const float*)d_in[3];
  const float* wo = (const float*)d_in[4];
  const float* bq = (const float*)d_in[5];
  const float* bk = (const float*)d_in[6];
  const float* bv = (const float*)d_in[7];
  float* out = (float*)d_out;

  const int M = B_ * L_;
  const int NQKV = NQKV_;                       // 2560
  const size_t QN = (size_t)B_ * L_ * HQ * DH;  // 8388608
  const size_t KN = (size_t)B_ * L_ * HKV * DH; // 1048576
  const size_t TN = (size_t)L_ * (DH / 2);      // 131072

  float* ws = (float*)d_ws;
  float* ct   = ws;
  float* st   = ct + TN;
  float* bqkv = st + TN;
  u16* qkvb   = (u16*)(bqkv + NQKV);        // bf16 QKV projection output
  u16* xb     = qkvb + (size_t)M * NQKV;    // x bf16
  u16* wqkvb  = xb + (size_t)M * E_;
  u16* ao     = wqkvb + (size_t)NQKV * E_;  // attention output (bf16)
  u16* Kbf    = ao + QN;
  u16* Vt     = Kbf + KN;
  u16* wob    = Vt + KN;                    // wo bf16

  rope_tab_kernel<<<(L_ * (DH / 2) + 255) / 256, 256, 0, stream>>>(ct, st);

  cvt_bf16_kernel<<<(int)(QN / 8 / 256), 256, 0, stream>>>(x, xb, (int)QN);
  cvt4_bf16_kernel<<<((NQKV + E_) * E_) / 8 / 256, 256, 0, stream>>>(
      wq, wk, wv, wo, wqkvb, wob,
      HQ * DH * E_, HKV * DH * E_, HKV * DH * E_, E_ * E_);
  bias_concat_kernel<<<(NQKV + 255) / 256, 256, 0, stream>>>(bq, bk, bv, bqkv);

  // fused QKV projection: [4096][2560] bf16 (grid 640, XCD-swizzled 1D)
  gemm_bf16_kernel<true><<<dim3((NQKV / GBN) * (M / GBM)), 256, 0, stream>>>(
      xb, wqkvb, bqkv, qkvb, M, NQKV, E_);

  // fused K-rope + V-transpose (one launch)
  kv_prep_kernel<<<dim3(KROPE_BLKS + 256), 256, 0, stream>>>(
      qkvb, Kbf, Vt, ct, st);

  flash_attn_pipe_kernel<<<dim3(512), 256, 0, stream>>>(
      qkvb, Kbf, Vt, ao, ct, st);

  // O-projection (grid 512, XCD-swizzled 1D)
  gemm_bf16_kernel<false><<<dim3((E_ / GBN) * (M / GBM)), 256, 0, stream>>>(
      ao, wob, nullptr, out, M, E_, E_);
}